// Round 8
// baseline (927.542 us; speedup 1.0000x reference)
//
#include <hip/hip_runtime.h>
#include <cstddef>
#include <cstdint>

// ---------------------------------------------------------------------------
// attention_net_noc: pointer-network decode step.
// R11: ONE persistent cooperative kernel (grid 256 x 1024thr, 16 waves/blk,
//      guaranteed co-resident) running all 8 phases with 7 grid barriers;
//      block 0 executes the combine bodies between barriers. Replaces
//      ~100 us of launch + 1-block-combine serialization (R10 accounting)
//      with ~20 us of in-kernel sync. Math = R9's verified 2-row path
//      (absmax 0). Fallback: if hipLaunchCooperativeKernel errors, the same
//      phase bodies run as 8 normal launches.
// R8 lesson respected: fences fire once per phase boundary (256 total),
// not per-block mid-stream; bulk L2->L3 writeback happens where a kernel
// boundary would drain anyway.
// ---------------------------------------------------------------------------

constexpr int NJ = 1000000;
constexpr int NM = 500000;
constexpr float NEGV = -1e8f;

constexpr int BLKP = 1024;            // threads/block = 16 waves
constexpr int NW   = BLKP / 64;       // 16 waves
constexpr int GRID = 256;             // cooperative grid: 1 block/CU
constexpr int TROWS = 2048;           // rows per tile (2 per thread)
constexpr int GB_JT = (NJ + TROWS - 1) / TROWS;   // 489
constexpr int GB_MT = (NM + TROWS - 1) / TROWS;   // 245
constexpr int GB_TT = GB_JT + GB_MT;              // 734
constexpr int EBLK = TROWS * 16;      // 32768 floats per E tile

// ---- workspace layout (float offsets from start of d_ws) ----
constexpr int S_QKJA = 0;    // 16: ja_Wq@g1 + ja_bq
constexpr int S_QK2J = 16;   // 16: aj_Wq@e_js + aj_bq   (contiguous with QK2M)
constexpr int S_QK2M = 32;   // 16: am_Wq@e_js + am_bq
constexpr int S_EJS  = 48;   // 16: E_j[sel_j]
constexpr int S_QKMA = 64;   // 16: ma_Wq@g2 + ma_bq
constexpr int S_LOGPJ = 80;
constexpr int S_SELJ  = 81;  // stored as float (exact, < 2^24)
constexpr int C_CTR   = 84;  // 2 uints: barrier counter + generation (memset 0)
constexpr int P1J = 128;                       // GB_JT*17 glimpse partials (l, s[16])
constexpr int P1M = P1J + GB_JT * 17;
constexpr int P2V = P1M + GB_MT * 17;          // GB_JT argmax vals (p7 reuses)
constexpr int P2I = P2V + GB_JT;
constexpr int P2L = P2I + GB_JT;
constexpr size_t E_OFF = 65536;                // float offset of E cache tiles
static_assert(P2L + GB_JT <= (int)E_OFF, "partials overflow into E cache");

typedef float v2f __attribute__((ext_vector_type(2)));

struct Params {
    const float *jobs, *machines;
    const int *mask;
    const float *jW1, *jb1, *jW2, *jb2;
    const float *mW1, *mb1, *mW2, *mb2;
    const float *aj_Wq, *aj_bq, *aj_Wr, *aj_V;
    const float *am_Wq, *am_bq, *am_Wr, *am_V;
    const float *ja_Wq, *ja_bq, *ja_Wr, *ja_V;
    const float *ma_Wq, *ma_bq, *ma_Wr, *ma_V;
    const float *g1W, *g1b, *g2W, *g2b, *last_j;
    float *S;        // smalls + partials (in ws)
    float *Ej, *Em;  // embedding cache tiles (in ws; valid only if CACHE)
    float *out;
};

// ---------------------------------------------------------------------------
// device helpers
// ---------------------------------------------------------------------------

// tanh(x) = 1 - 2*rcp(exp2(x*2*log2e)+1). 5 instrs. abs err ~2e-7 vs np.tanh.
__device__ __forceinline__ float fast_tanh(float x) {
    float e = __builtin_amdgcn_exp2f(x * 2.8853900817779268f);  // 2/ln2
    float r = __builtin_amdgcn_rcpf(e + 1.0f);
    return fmaf(-2.0f, r, 1.0f);
}

__device__ __forceinline__ v2f vbc(float a) { v2f r; r.x = a; r.y = a; return r; }

__device__ __forceinline__ v2f vfma(float w, v2f b, v2f c) {
    return __builtin_elementwise_fma(vbc(w), b, c);
}
__device__ __forceinline__ v2f vfma2(v2f a, v2f b, v2f c) {
    return __builtin_elementwise_fma(a, b, c);
}
__device__ __forceinline__ v2f vtanh(v2f a) {
    v2f r; r.x = fast_tanh(a.x); r.y = fast_tanh(a.y); return r;
}

__device__ __forceinline__ void load16(const float* __restrict__ X, size_t r, float (&x)[16]) {
    const float4* p4 = reinterpret_cast<const float4*>(X) + r * 4;
    float4 a = p4[0], b = p4[1], c = p4[2], d = p4[3];
    x[0]=a.x; x[1]=a.y; x[2]=a.z; x[3]=a.w;
    x[4]=b.x; x[5]=b.y; x[6]=b.z; x[7]=b.w;
    x[8]=c.x; x[9]=c.y; x[10]=c.z; x[11]=c.w;
    x[12]=d.x; x[13]=d.y; x[14]=d.z; x[15]=d.w;
}

__device__ __forceinline__ void load16_v2(const float* __restrict__ X, size_t rA, size_t rB,
                                          v2f (&x)[16]) {
    float a[16], b[16];
    load16(X, rA, a);
    load16(X, rB, b);
#pragma unroll
    for (int k = 0; k < 16; ++k) { x[k].x = a[k]; x[k].y = b[k]; }
}

// E tile: [8][1024 threads * float4 {e2k(rA,rB), e2k+1(rA,rB)}], rows (2t,2t+1)
__device__ __forceinline__ void ecache_store(float* __restrict__ Eb, int t, const v2f (&e)[16]) {
    float4* p4 = reinterpret_cast<float4*>(Eb);
#pragma unroll
    for (int kp = 0; kp < 8; ++kp)
        p4[kp * BLKP + t] = make_float4(e[2*kp].x, e[2*kp].y, e[2*kp+1].x, e[2*kp+1].y);
}
__device__ __forceinline__ void ecache_load(const float* __restrict__ Eb, int t, v2f (&e)[16]) {
    const float4* p4 = reinterpret_cast<const float4*>(Eb);
#pragma unroll
    for (int kp = 0; kp < 8; ++kp) {
        float4 q = p4[kp * BLKP + t];
        e[2*kp].x = q.x;   e[2*kp].y = q.y;
        e[2*kp+1].x = q.z; e[2*kp+1].y = q.w;
    }
}

__device__ __forceinline__ void emb16_v2(const v2f (&x)[16],
                                         const float* __restrict__ W1, const float* __restrict__ b1,
                                         const float* __restrict__ W2, const float* __restrict__ b2,
                                         v2f (&e)[16]) {
    v2f h[16];
#pragma unroll
    for (int i = 0; i < 16; ++i) {
        v2f a = vbc(b1[i]);
#pragma unroll
        for (int k = 0; k < 16; ++k) a = vfma(W1[i * 16 + k], x[k], a);
        h[i] = vtanh(a);
    }
#pragma unroll
    for (int i = 0; i < 16; ++i) {
        v2f a = vbc(b2[i]);
#pragma unroll
        for (int k = 0; k < 16; ++k) a = vfma(W2[i * 16 + k], h[k], a);
        e[i] = vtanh(a);
    }
}

__device__ __forceinline__ v2f att_logit_v2(const v2f (&e)[16], const float (&qk)[16],
                                            const float* __restrict__ Wr,
                                            const float* __restrict__ V) {
    v2f acc = vbc(0.0f);
#pragma unroll
    for (int i = 0; i < 16; ++i) {
        v2f r = vbc(qk[i]);
#pragma unroll
        for (int k = 0; k < 16; ++k) r = vfma(Wr[i * 16 + k], e[k], r);
        acc = vfma2(vbc(V[i]), vtanh(r), acc);
    }
    return acc;
}

__device__ __forceinline__ float wave_reduce_sum(float v) {
#pragma unroll
    for (int off = 32; off > 0; off >>= 1) v += __shfl_xor(v, off, 64);
    return v;
}

__device__ __forceinline__ void wave_reduce_argmax(float &v, int &idx) {
#pragma unroll
    for (int off = 32; off > 0; off >>= 1) {
        float ov = __shfl_xor(v, off, 64);
        int oi = __shfl_xor(idx, off, 64);
        if (ov > v || (ov == v && oi < idx)) { v = ov; idx = oi; }
    }
}

__device__ __forceinline__ float block_sum(float v) {
    __shared__ float sm[NW];
    v = wave_reduce_sum(v);
    __syncthreads();
    if ((threadIdx.x & 63) == 0) sm[threadIdx.x >> 6] = v;
    __syncthreads();
    float t = 0.0f;
#pragma unroll
    for (int k = 0; k < NW; ++k) t += sm[k];
    return t;
}

__device__ __forceinline__ void block_argmax(float &v, int &i) {
    __shared__ float sv[NW];
    __shared__ int si[NW];
    wave_reduce_argmax(v, i);
    __syncthreads();
    if ((threadIdx.x & 63) == 0) { sv[threadIdx.x >> 6] = v; si[threadIdx.x >> 6] = i; }
    __syncthreads();
    float bv = sv[0]; int bi = si[0];
#pragma unroll
    for (int k = 1; k < NW; ++k)
        if (sv[k] > bv || (sv[k] == bv && si[k] < bi)) { bv = sv[k]; bi = si[k]; }
    v = bv; i = bi;
}

// Block-reduce (l, s[16]) -> dst[17] via reduce-scatter butterflies.
// OUTPUT LAYOUT (contract with all readers): dst[0] = l, dst[1+j] = s[j].
// Verified in R7/R9/R10 (absmax 0 across all sites). Loop-safe (leading sync).
__device__ __forceinline__ void block_sum17(float l, const float (&s)[16], float* dst) {
    const int lane = threadIdx.x & 63;
    float c[8];
#pragma unroll
    for (int j = 0; j < 8; ++j) {          // xor 1: 16 -> 8
        const bool hi = lane & 1;
        float t = __shfl_xor(hi ? s[j] : s[j + 8], 1, 64);
        c[j] = (hi ? s[j + 8] : s[j]) + t;
    }
    float d[4];
#pragma unroll
    for (int j = 0; j < 4; ++j) {          // xor 2: 8 -> 4
        const bool hi = lane & 2;
        float t = __shfl_xor(hi ? c[j] : c[j + 4], 2, 64);
        d[j] = (hi ? c[j + 4] : c[j]) + t;
    }
    float e2[2];
#pragma unroll
    for (int j = 0; j < 2; ++j) {          // xor 4: 4 -> 2
        const bool hi = lane & 4;
        float t = __shfl_xor(hi ? d[j] : d[j + 2], 4, 64);
        e2[j] = (hi ? d[j + 2] : d[j]) + t;
    }
    float f;
    {                                       // xor 8: 2 -> 1
        const bool hi = lane & 8;
        float t = __shfl_xor(hi ? e2[0] : e2[1], 8, 64);
        f = (hi ? e2[1] : e2[0]) + t;
    }
    f += __shfl_xor(f, 16, 64);             // merge 16-lane groups
    f += __shfl_xor(f, 32, 64);
#pragma unroll
    for (int off = 32; off > 0; off >>= 1) l += __shfl_xor(l, off, 64);

    const int idx = ((lane & 1) << 3) | ((lane & 2) << 1) | ((lane & 4) >> 1) | ((lane & 8) >> 3);
    __shared__ float red[NW][17];
    const int w = threadIdx.x >> 6;
    __syncthreads();                        // guard reuse across successive calls
    if (lane < 16) red[w][1 + idx] = f;     // s[idx] -> dst[1+idx]
    if (lane == 0) red[w][0] = l;           // l      -> dst[0]
    __syncthreads();
    if (threadIdx.x < 17) {
        float t = 0.0f;
#pragma unroll
        for (int k = 0; k < NW; ++k) t += red[k][threadIdx.x];
        dst[threadIdx.x] = t;
    }
}

// Sense-reversing grid barrier (cooperative launch guarantees co-residency).
// Release/acquire at agent scope; fires once per block per phase boundary.
__device__ __forceinline__ void grid_sync(unsigned* ctr, unsigned* gen) {
    __syncthreads();
    if (threadIdx.x == 0) {
        __threadfence();   // release: flush this block's stores to coherence point
        unsigned g = __hip_atomic_load(gen, __ATOMIC_RELAXED, __HIP_MEMORY_SCOPE_AGENT);
        if (__hip_atomic_fetch_add(ctr, 1u, __ATOMIC_ACQ_REL, __HIP_MEMORY_SCOPE_AGENT)
            == gridDim.x - 1) {
            __hip_atomic_store(ctr, 0u, __ATOMIC_RELAXED, __HIP_MEMORY_SCOPE_AGENT);
            __hip_atomic_store(gen, g + 1u, __ATOMIC_RELEASE, __HIP_MEMORY_SCOPE_AGENT);
        } else {
            while (__hip_atomic_load(gen, __ATOMIC_ACQUIRE, __HIP_MEMORY_SCOPE_AGENT) == g)
                __builtin_amdgcn_s_sleep(10);
        }
        __threadfence();   // acquire: invalidate stale cached lines
    }
    __syncthreads();
}

// ---------------------------------------------------------------------------
// combine bodies (BLKP threads; run by block 0 of the persistent kernel, or
// by dedicated 1-block kernels in the fallback path)
// ---------------------------------------------------------------------------

__device__ __forceinline__ void combine_g_body(const Params& p, int phase) {
    const float* PJ = p.S + P1J;
    const float* PM = p.S + P1M;
    float lJ = 0.0f, lM = 0.0f, sJ[16], sM[16];
#pragma unroll
    for (int c = 0; c < 16; ++c) { sJ[c] = 0.0f; sM[c] = 0.0f; }
    for (int i = threadIdx.x; i < GB_JT; i += BLKP) {
        lJ += PJ[i * 17];
#pragma unroll
        for (int c = 0; c < 16; ++c) sJ[c] += PJ[i * 17 + 1 + c];
    }
    for (int i = threadIdx.x; i < GB_MT; i += BLKP) {
        lM += PM[i * 17];
#pragma unroll
        for (int c = 0; c < 16; ++c) sM[c] += PM[i * 17 + 1 + c];
    }
    __shared__ float totJ[17], totM[17];
    block_sum17(lJ, sJ, totJ);
    block_sum17(lM, sM, totM);
    __syncthreads();

    __shared__ float cb[48], gbuf[16];
    if (threadIdx.x < 16) {
        int i = threadIdx.x;
        cb[i]      = phase ? p.S[S_EJS + i] : p.last_j[i];
        cb[16 + i] = totJ[1 + i] / totJ[0];   // softmax-weighted sum / partition
        cb[32 + i] = totM[1 + i] / totM[0];
    }
    __syncthreads();
    const float* gW  = phase ? p.g2W : p.g1W;
    const float* gbv = phase ? p.g2b : p.g1b;
    if (threadIdx.x < 16) {
        int i = threadIdx.x;
        float a = gbv[i];
#pragma unroll
        for (int k = 0; k < 48; ++k) a = fmaf(gW[i * 48 + k], cb[k], a);
        gbuf[i] = fast_tanh(a);
    }
    __syncthreads();
    const float* Wq = phase ? p.ma_Wq : p.ja_Wq;
    const float* bq = phase ? p.ma_bq : p.ja_bq;
    const int off = phase ? S_QKMA : S_QKJA;
    if (threadIdx.x < 16) {
        int i = threadIdx.x;
        float a = bq[i];
#pragma unroll
        for (int k = 0; k < 16; ++k) a = fmaf(Wq[i * 16 + k], gbuf[k], a);
        p.S[off + i] = a;
    }
}

__device__ __forceinline__ void combine2_body(const Params& p) {
    float v = -3.4e38f; int vi = 0x7fffffff; float l = 0.0f;
    for (int i = threadIdx.x; i < GB_JT; i += BLKP) {
        float pv = p.S[P2V + i];
        int pi = (int)p.S[P2I + i];
        if (pv > v || (pv == v && pi < vi)) { v = pv; vi = pi; }
        l += p.S[P2L + i];
    }
    l = block_sum(l);
    block_argmax(v, vi);
    const int sel = vi;

    __shared__ float xb[16], hb[16], eb[16];
    if (threadIdx.x < 16) xb[threadIdx.x] = p.jobs[(size_t)sel * 16 + threadIdx.x];
    __syncthreads();
    if (threadIdx.x < 16) {
        int i = threadIdx.x;
        float a = p.jb1[i];
#pragma unroll
        for (int k = 0; k < 16; ++k) a = fmaf(p.jW1[i * 16 + k], xb[k], a);
        hb[i] = fast_tanh(a);
    }
    __syncthreads();
    if (threadIdx.x < 16) {
        int i = threadIdx.x;
        float a = p.jb2[i];
#pragma unroll
        for (int k = 0; k < 16; ++k) a = fmaf(p.jW2[i * 16 + k], hb[k], a);
        float e = fast_tanh(a);
        eb[i] = e;
        p.S[S_EJS + i] = e;
    }
    __syncthreads();
    if (threadIdx.x < 16) {
        int i = threadIdx.x;
        float a1 = p.aj_bq[i], a2 = p.am_bq[i];
#pragma unroll
        for (int k = 0; k < 16; ++k) {
            a1 = fmaf(p.aj_Wq[i * 16 + k], eb[k], a1);
            a2 = fmaf(p.am_Wq[i * 16 + k], eb[k], a2);
        }
        p.S[S_QK2J + i] = a1;
        p.S[S_QK2M + i] = a2;
    }
    if (threadIdx.x == 0) {
        p.S[S_LOGPJ] = v - logf(l);     // log_softmax at the argmax
        p.S[S_SELJ] = (float)sel;
    }
}

__device__ __forceinline__ void combine4_body(const Params& p) {
    float v = -3.4e38f; int vi = 0x7fffffff; float l = 0.0f;
    for (int i = threadIdx.x; i < GB_MT; i += BLKP) {
        float pv = p.S[P2V + i];
        int pi = (int)p.S[P2I + i];
        if (pv > v || (pv == v && pi < vi)) { v = pv; vi = pi; }
        l += p.S[P2L + i];
    }
    l = block_sum(l);
    block_argmax(v, vi);
    if (threadIdx.x == 0) {
        p.out[0] = p.S[S_SELJ];
        p.out[1] = (float)vi;
        p.out[2] = p.S[S_LOGPJ] + (v - logf(l));
    }
}

// ---------------------------------------------------------------------------
// phase bodies (grid-stride over tiles; used by persistent AND fallback paths)
// ---------------------------------------------------------------------------

__device__ __forceinline__ void init_qk1(const Params& p, float* qk1j, float* qk1m) {
    if (threadIdx.x < 32) {
        const bool isJ = threadIdx.x < 16;
        const int i = threadIdx.x & 15;
        const float* Wq = isJ ? p.aj_Wq : p.am_Wq;
        const float* bq = isJ ? p.aj_bq : p.am_bq;
        float a = bq[i];
#pragma unroll
        for (int k = 0; k < 16; ++k) a = fmaf(Wq[i * 16 + k], p.last_j[k], a);
        (isJ ? qk1j : qk1m)[i] = a;
    }
    __syncthreads();
}

// P1: embeddings (cached if CACHE) + glimpse-1 partials
template <bool CACHE>
__device__ __forceinline__ void run_p1(const Params& p, const float* qk1j, const float* qk1m) {
    for (int tile = blockIdx.x; tile < GB_TT; tile += gridDim.x) {
        const bool isJob = tile < GB_JT;
        const float* X  = isJob ? p.jobs : p.machines;
        const float* W1 = isJob ? p.jW1 : p.mW1;
        const float* b1 = isJob ? p.jb1 : p.mb1;
        const float* W2 = isJob ? p.jW2 : p.mW2;
        const float* b2 = isJob ? p.jb2 : p.mb2;
        const float* Wr = isJob ? p.aj_Wr : p.am_Wr;
        const float* V  = isJob ? p.aj_V  : p.am_V;
        float* E = isJob ? p.Ej : p.Em;
        const int n  = isJob ? NJ : NM;
        const int b0 = isJob ? tile : tile - GB_JT;

        float qk[16];
        const float* qsrc = isJob ? qk1j : qk1m;
#pragma unroll
        for (int i = 0; i < 16; ++i) qk[i] = qsrc[i];

        const int r0 = b0 * TROWS + 2 * (int)threadIdx.x;
        const bool v = r0 < n;             // n even => r0,r0+1 valid together
        const size_t a0 = v ? (size_t)r0 : 0;
        const size_t a1 = a0 + (v ? 1 : 0);

        v2f x[16], e[16];
        load16_v2(X, a0, a1, x);
        emb16_v2(x, W1, b1, W2, b2, e);
        if (CACHE) ecache_store(E + (size_t)b0 * EBLK, (int)threadIdx.x, e);
        v2f lg = att_logit_v2(e, qk, Wr, V);
        // |logit| <= sum|V| ~ 0.6 -> exp never overflows; no max-shift needed.
        float pw0 = v ? __expf(lg.x) : 0.0f;
        float pw1 = v ? __expf(lg.y) : 0.0f;
        float l = pw0 + pw1, s[16];
#pragma unroll
        for (int i = 0; i < 16; ++i) s[i] = fmaf(pw0, e[i].x, pw1 * e[i].y);

        block_sum17(l, s, p.S + (isJob ? P1J : P1M) + (size_t)b0 * 17);
    }
}

// P3: job pointer logits -> masked argmax + sum-exp partials
template <bool CACHE>
__device__ __forceinline__ void run_p3(const Params& p) {
    float qk[16];
#pragma unroll
    for (int i = 0; i < 16; ++i) qk[i] = p.S[S_QKJA + i];

    for (int tile = blockIdx.x; tile < GB_JT; tile += gridDim.x) {
        const int r0 = tile * TROWS + 2 * (int)threadIdx.x;
        const bool v = r0 < NJ;
        const size_t a0 = v ? (size_t)r0 : 0;
        const size_t a1 = a0 + (v ? 1 : 0);

        v2f e[16];
        if (CACHE) {
            ecache_load(p.Ej + (size_t)tile * EBLK, (int)threadIdx.x, e);
        } else {
            v2f x[16];
            load16_v2(p.jobs, a0, a1, x);
            emb16_v2(x, p.jW1, p.jb1, p.jW2, p.jb2, e);
        }
        v2f lg = att_logit_v2(e, qk, p.ja_Wr, p.ja_V);

        int2 mq = make_int2(0, 0);
        if (v) mq = *reinterpret_cast<const int2*>(p.mask + r0);   // r0 even -> 8B aligned
        const bool m0 = v && (mq.x != 0);
        const bool m1 = v && (mq.y != 0);
        float l = (m0 ? __expf(lg.x) : 0.0f) + (m1 ? __expf(lg.y) : 0.0f);
        float am0 = m0 ? lg.x : NEGV - 1.0f;   // invalid rows below masked NEG
        float am1 = m1 ? lg.y : NEGV - 1.0f;
        float best;
        int bi;
        if (am0 >= am1) { best = am0; bi = r0; }
        else            { best = am1; bi = r0 + 1; }

        l = wave_reduce_sum(l);
        wave_reduce_argmax(best, bi);
        __shared__ float rl[NW], rv[NW];
        __shared__ int ri[NW];
        int w = threadIdx.x >> 6, ln = threadIdx.x & 63;
        __syncthreads();                    // guard reuse across tile loop
        if (ln == 0) { rl[w] = l; rv[w] = best; ri[w] = bi; }
        __syncthreads();
        if (threadIdx.x == 0) {
            float L = 0.0f;
#pragma unroll
            for (int k = 0; k < NW; ++k) L += rl[k];
            float vv = rv[0]; int i = ri[0];
#pragma unroll
            for (int k = 1; k < NW; ++k)
                if (rv[k] > vv || (rv[k] == vv && ri[k] < i)) { vv = rv[k]; i = ri[k]; }
            p.S[P2V + tile] = vv;
            p.S[P2I + tile] = (float)i;     // exact: i < 2^24
            p.S[P2L + tile] = L;
        }
    }
}

// P5: glimpse-2 over jobs (aj_*) and machines (am_*), query e_js
template <bool CACHE>
__device__ __forceinline__ void run_p5(const Params& p) {
    __shared__ float q2[32];                // S_QK2J(16) + S_QK2M(16), contiguous
    if (threadIdx.x < 32) q2[threadIdx.x] = p.S[S_QK2J + threadIdx.x];
    __syncthreads();

    for (int tile = blockIdx.x; tile < GB_TT; tile += gridDim.x) {
        const bool isJob = tile < GB_JT;
        const float* Wr = isJob ? p.aj_Wr : p.am_Wr;
        const float* V  = isJob ? p.aj_V  : p.am_V;
        const float* E  = isJob ? p.Ej : p.Em;
        const float* X  = isJob ? p.jobs : p.machines;
        const float* W1 = isJob ? p.jW1 : p.mW1;
        const float* b1 = isJob ? p.jb1 : p.mb1;
        const float* W2 = isJob ? p.jW2 : p.mW2;
        const float* b2 = isJob ? p.jb2 : p.mb2;
        const int n  = isJob ? NJ : NM;
        const int b0 = isJob ? tile : tile - GB_JT;

        float qk[16];
        const float* qsrc = q2 + (isJob ? 0 : 16);
#pragma unroll
        for (int i = 0; i < 16; ++i) qk[i] = qsrc[i];

        const int r0 = b0 * TROWS + 2 * (int)threadIdx.x;
        const bool v = r0 < n;
        const size_t a0 = v ? (size_t)r0 : 0;
        const size_t a1 = a0 + (v ? 1 : 0);

        v2f e[16];
        if (CACHE) {
            ecache_load(E + (size_t)b0 * EBLK, (int)threadIdx.x, e);
        } else {
            v2f x[16];
            load16_v2(X, a0, a1, x);
            emb16_v2(x, W1, b1, W2, b2, e);
        }
        v2f lg = att_logit_v2(e, qk, Wr, V);
        float pw0 = v ? __expf(lg.x) : 0.0f;
        float pw1 = v ? __expf(lg.y) : 0.0f;
        float l = pw0 + pw1, s[16];
#pragma unroll
        for (int i = 0; i < 16; ++i) s[i] = fmaf(pw0, e[i].x, pw1 * e[i].y);

        block_sum17(l, s, p.S + (isJob ? P1J : P1M) + (size_t)b0 * 17);
    }
}

// P7: machine logits -> argmax + sum-exp partials
template <bool CACHE>
__device__ __forceinline__ void run_p7(const Params& p) {
    float qk[16];
#pragma unroll
    for (int i = 0; i < 16; ++i) qk[i] = p.S[S_QKMA + i];

    for (int tile = blockIdx.x; tile < GB_MT; tile += gridDim.x) {
        const int r0 = tile * TROWS + 2 * (int)threadIdx.x;
        const bool v = r0 < NM;
        const size_t a0 = v ? (size_t)r0 : 0;
        const size_t a1 = a0 + (v ? 1 : 0);

        v2f e[16];
        if (CACHE) {
            ecache_load(p.Em + (size_t)tile * EBLK, (int)threadIdx.x, e);
        } else {
            v2f x[16];
            load16_v2(p.machines, a0, a1, x);
            emb16_v2(x, p.mW1, p.mb1, p.mW2, p.mb2, e);
        }
        v2f lg = att_logit_v2(e, qk, p.ma_Wr, p.ma_V);
        float l = (v ? __expf(lg.x) : 0.0f) + (v ? __expf(lg.y) : 0.0f);
        float am0 = v ? lg.x : -3.4e38f;
        float am1 = v ? lg.y : -3.4e38f;
        float best;
        int bi;
        if (am0 >= am1) { best = am0; bi = r0; }
        else            { best = am1; bi = r0 + 1; }

        l = wave_reduce_sum(l);
        wave_reduce_argmax(best, bi);
        __shared__ float rl[NW], rv[NW];
        __shared__ int ri[NW];
        int w = threadIdx.x >> 6, ln = threadIdx.x & 63;
        __syncthreads();                    // guard reuse across tile loop
        if (ln == 0) { rl[w] = l; rv[w] = best; ri[w] = bi; }
        __syncthreads();
        if (threadIdx.x == 0) {
            float L = 0.0f;
#pragma unroll
            for (int k = 0; k < NW; ++k) L += rl[k];
            float vv = rv[0]; int i = ri[0];
#pragma unroll
            for (int k = 1; k < NW; ++k)
                if (rv[k] > vv || (rv[k] == vv && ri[k] < i)) { vv = rv[k]; i = ri[k]; }
            p.S[P2V + tile] = vv;
            p.S[P2I + tile] = (float)i;
            p.S[P2L + tile] = L;
        }
    }
}

// ---------------------------------------------------------------------------
// Persistent cooperative kernel: all 8 phases, 7 grid barriers.
// ---------------------------------------------------------------------------
template <bool CACHE>
__global__ __launch_bounds__(BLKP, 4) void k_all(Params p) {
    __shared__ float qk1j[16], qk1m[16];
    init_qk1(p, qk1j, qk1m);
    unsigned* ctr = reinterpret_cast<unsigned*>(p.S + C_CTR);
    unsigned* gen = ctr + 1;

    run_p1<CACHE>(p, qk1j, qk1m);
    grid_sync(ctr, gen);
    if (blockIdx.x == 0) combine_g_body(p, 0);
    grid_sync(ctr, gen);
    run_p3<CACHE>(p);
    grid_sync(ctr, gen);
    if (blockIdx.x == 0) combine2_body(p);
    grid_sync(ctr, gen);
    run_p5<CACHE>(p);
    grid_sync(ctr, gen);
    if (blockIdx.x == 0) combine_g_body(p, 1);
    grid_sync(ctr, gen);
    run_p7<CACHE>(p);
    grid_sync(ctr, gen);
    if (blockIdx.x == 0) combine4_body(p);
}

// ---------------------------------------------------------------------------
// Fallback kernels (normal launches; grid covers all tiles -> 1 tile/block)
// ---------------------------------------------------------------------------
template <bool CACHE>
__global__ __launch_bounds__(BLKP, 4) void k_p1(Params p) {
    __shared__ float qk1j[16], qk1m[16];
    init_qk1(p, qk1j, qk1m);
    run_p1<CACHE>(p, qk1j, qk1m);
}
template <bool CACHE>
__global__ __launch_bounds__(BLKP, 4) void k_p3(Params p) { run_p3<CACHE>(p); }
template <bool CACHE>
__global__ __launch_bounds__(BLKP, 4) void k_p5(Params p) { run_p5<CACHE>(p); }
template <bool CACHE>
__global__ __launch_bounds__(BLKP, 4) void k_p7(Params p) { run_p7<CACHE>(p); }
__global__ __launch_bounds__(BLKP, 4) void k_cg(Params p, int phase) { combine_g_body(p, phase); }
__global__ __launch_bounds__(BLKP, 4) void k_c2(Params p) { combine2_body(p); }
__global__ __launch_bounds__(BLKP, 4) void k_c4(Params p) { combine4_body(p); }

// ---------------------------------------------------------------------------
extern "C" void kernel_launch(void* const* d_in, const int* in_sizes, int n_in,
                              void* d_out, int out_size, void* d_ws, size_t ws_size,
                              hipStream_t stream) {
    Params p;
    p.jobs     = (const float*)d_in[0];
    p.machines = (const float*)d_in[1];
    p.mask     = (const int*)d_in[2];
    p.jW1 = (const float*)d_in[3];  p.jb1 = (const float*)d_in[4];
    p.jW2 = (const float*)d_in[5];  p.jb2 = (const float*)d_in[6];
    p.mW1 = (const float*)d_in[7];  p.mb1 = (const float*)d_in[8];
    p.mW2 = (const float*)d_in[9];  p.mb2 = (const float*)d_in[10];
    p.aj_Wq = (const float*)d_in[11]; p.aj_bq = (const float*)d_in[12];
    p.aj_Wr = (const float*)d_in[13]; p.aj_V  = (const float*)d_in[14];
    p.am_Wq = (const float*)d_in[15]; p.am_bq = (const float*)d_in[16];
    p.am_Wr = (const float*)d_in[17]; p.am_V  = (const float*)d_in[18];
    p.ja_Wq = (const float*)d_in[19]; p.ja_bq = (const float*)d_in[20];
    p.ja_Wr = (const float*)d_in[21]; p.ja_V  = (const float*)d_in[22];
    p.ma_Wq = (const float*)d_in[23]; p.ma_bq = (const float*)d_in[24];
    p.ma_Wr = (const float*)d_in[25]; p.ma_V  = (const float*)d_in[26];
    p.g1W = (const float*)d_in[27]; p.g1b = (const float*)d_in[28];
    p.g2W = (const float*)d_in[29]; p.g2b = (const float*)d_in[30];
    p.last_j = (const float*)d_in[31];
    p.S = (float*)d_ws;
    p.Ej = (float*)d_ws + E_OFF;
    p.Em = p.Ej + (size_t)GB_JT * EBLK;
    p.out = (float*)d_out;

    const size_t needed = (E_OFF + (size_t)GB_TT * EBLK) * sizeof(float);
    const bool cache = ws_size >= needed;

    // zero the barrier counter+generation (8 bytes)
    hipMemsetAsync((char*)d_ws + (size_t)C_CTR * sizeof(float), 0, 2 * sizeof(unsigned), stream);

    void* args[] = { &p };
    hipError_t err = hipLaunchCooperativeKernel(
        cache ? reinterpret_cast<const void*>(&k_all<true>)
              : reinterpret_cast<const void*>(&k_all<false>),
        dim3(GRID), dim3(BLKP), args, 0, stream);

    if (err != hipSuccess) {
        (void)hipGetLastError();   // clear error state; use multi-launch path
        if (cache) {
            k_p1<true><<<GB_TT, BLKP, 0, stream>>>(p);
            k_cg<<<1, BLKP, 0, stream>>>(p, 0);
            k_p3<true><<<GB_JT, BLKP, 0, stream>>>(p);
            k_c2<<<1, BLKP, 0, stream>>>(p);
            k_p5<true><<<GB_TT, BLKP, 0, stream>>>(p);
            k_cg<<<1, BLKP, 0, stream>>>(p, 1);
            k_p7<true><<<GB_MT, BLKP, 0, stream>>>(p);
            k_c4<<<1, BLKP, 0, stream>>>(p);
        } else {
            k_p1<false><<<GB_TT, BLKP, 0, stream>>>(p);
            k_cg<<<1, BLKP, 0, stream>>>(p, 0);
            k_p3<false><<<GB_JT, BLKP, 0, stream>>>(p);
            k_c2<<<1, BLKP, 0, stream>>>(p);
            k_p5<false><<<GB_TT, BLKP, 0, stream>>>(p);
            k_cg<<<1, BLKP, 0, stream>>>(p, 1);
            k_p7<false><<<GB_MT, BLKP, 0, stream>>>(p);
            k_c4<<<1, BLKP, 0, stream>>>(p);
        }
    }
}

// Round 9
// 310.321 us; speedup vs baseline: 2.9890x; 2.9890x over previous
//
#include <hip/hip_runtime.h>
#include <cstddef>
#include <cstdint>

// ---------------------------------------------------------------------------
// attention_net_noc: pointer-network decode step.
// R12 = R10 (286.9 us best: 4 rows/thread, E-cache float4 tiles, reduce-
//       scatter sum17) with the 3 mid-pipeline combine kernels FOLDED into
//       redundant per-block prologues of the following sweep:
//   B' (jlogits):  every block recomputes g1->qkJA from A's P1 partials.
//   C' (glimpse2): every block recomputes sel_j -> e_js -> qk2j/qk2m from P2.
//   D' (mlogits):  every block recomputes sel_j/logp_j + g2->qkMA from P2+P1;
//                  writes its own partials to a NEW P3 buffer (avoids the
//                  intra-kernel P2 read/write race).
// All blocks compute bit-identical combine results (same inputs, same order)
// -> deterministic; cross-kernel dataflow stays at kernel boundaries ONLY.
// R8/R11 lesson (final): ticket fences AND cooperative grid barriers both
// poison L2 on gfx950 (R8: 6x, R11: 911 MB HBM traffic, 3.2x). Kernel
// boundaries are the only cheap sync on this chip. 8 launches -> 5.
// ---------------------------------------------------------------------------

constexpr int NJ = 1000000;
constexpr int NM = 500000;
constexpr float NEGV = -1e8f;

constexpr int BLK = 256;
constexpr int ROWS_PER_BLK = 1024;           // 4 adjacent rows per thread
constexpr int GB_J = (NJ + ROWS_PER_BLK - 1) / ROWS_PER_BLK;   // 977
constexpr int GB_M = (NM + ROWS_PER_BLK - 1) / ROWS_PER_BLK;   // 489
constexpr int GB_TOT = GB_J + GB_M;                             // 1466
constexpr int EBLK = ROWS_PER_BLK * 16;                         // 16384 floats/tile

// ---- workspace layout (float offsets from start of d_ws) ----
constexpr int S_LOGPJ = 80;
constexpr int S_SELJ  = 81;  // stored as float (exact, < 2^24)
constexpr int P1J = 128;                       // GB_J*17 glimpse partials (l, s[16])
constexpr int P1M = P1J + GB_J * 17;
constexpr int P2V = P1M + GB_M * 17;           // GB_J job-argmax partials
constexpr int P2I = P2V + GB_J;
constexpr int P2L = P2I + GB_J;
constexpr int P3V = P2L + GB_J;                // GB_M machine-argmax partials (D')
constexpr int P3I = P3V + GB_M;
constexpr int P3L = P3I + GB_M;
constexpr size_t E_OFF = 65536;                // float offset of E cache tiles
static_assert(P3L + GB_M <= (int)E_OFF, "partials overflow into E cache");
static_assert(NJ % 4 == 0 && NM % 4 == 0, "4-row packing needs n % 4 == 0");

typedef float v2f __attribute__((ext_vector_type(2)));

struct Params {
    const float *jobs, *machines;
    const int *mask;
    const float *jW1, *jb1, *jW2, *jb2;
    const float *mW1, *mb1, *mW2, *mb2;
    const float *aj_Wq, *aj_bq, *aj_Wr, *aj_V;
    const float *am_Wq, *am_bq, *am_Wr, *am_V;
    const float *ja_Wq, *ja_bq, *ja_Wr, *ja_V;
    const float *ma_Wq, *ma_bq, *ma_Wr, *ma_V;
    const float *g1W, *g1b, *g2W, *g2b, *last_j;
    float *S;        // smalls + partials (in ws)
    float *Ej, *Em;  // embedding cache tiles (in ws; valid only if CACHE)
    float *out;
};

// ---------------------------------------------------------------------------
// device helpers (verified R9/R10 versions, unchanged)
// ---------------------------------------------------------------------------

__device__ __forceinline__ float fast_tanh(float x) {
    float e = __builtin_amdgcn_exp2f(x * 2.8853900817779268f);  // 2/ln2
    float r = __builtin_amdgcn_rcpf(e + 1.0f);
    return fmaf(-2.0f, r, 1.0f);
}

__device__ __forceinline__ v2f vbc(float a) { v2f r; r.x = a; r.y = a; return r; }

__device__ __forceinline__ v2f vfma(float w, v2f b, v2f c) {
    return __builtin_elementwise_fma(vbc(w), b, c);
}
__device__ __forceinline__ v2f vfma2(v2f a, v2f b, v2f c) {
    return __builtin_elementwise_fma(a, b, c);
}
__device__ __forceinline__ v2f vtanh(v2f a) {
    v2f r; r.x = fast_tanh(a.x); r.y = fast_tanh(a.y); return r;
}

__device__ __forceinline__ void load16(const float* __restrict__ X, size_t r, float (&x)[16]) {
    const float4* p4 = reinterpret_cast<const float4*>(X) + r * 4;
    float4 a = p4[0], b = p4[1], c = p4[2], d = p4[3];
    x[0]=a.x; x[1]=a.y; x[2]=a.z; x[3]=a.w;
    x[4]=b.x; x[5]=b.y; x[6]=b.z; x[7]=b.w;
    x[8]=c.x; x[9]=c.y; x[10]=c.z; x[11]=c.w;
    x[12]=d.x; x[13]=d.y; x[14]=d.z; x[15]=d.w;
}

__device__ __forceinline__ void load16_v2(const float* __restrict__ X, size_t rA, size_t rB,
                                          v2f (&x)[16]) {
    float a[16], b[16];
    load16(X, rA, a);
    load16(X, rB, b);
#pragma unroll
    for (int k = 0; k < 16; ++k) { x[k].x = a[k]; x[k].y = b[k]; }
}

// E-cache tile for 4 rows/thread: [8][2 pairs][256 threads * float4].
__device__ __forceinline__ void ecache_store4(float* __restrict__ Eb, int t,
                                              const v2f (&e0)[16], const v2f (&e1)[16]) {
    float4* p4 = reinterpret_cast<float4*>(Eb);
#pragma unroll
    for (int kp = 0; kp < 8; ++kp) {
        p4[kp * 512 + t]       = make_float4(e0[2*kp].x, e0[2*kp].y, e0[2*kp+1].x, e0[2*kp+1].y);
        p4[kp * 512 + 256 + t] = make_float4(e1[2*kp].x, e1[2*kp].y, e1[2*kp+1].x, e1[2*kp+1].y);
    }
}
__device__ __forceinline__ void ecache_load4(const float* __restrict__ Eb, int t,
                                             v2f (&e0)[16], v2f (&e1)[16]) {
    const float4* p4 = reinterpret_cast<const float4*>(Eb);
#pragma unroll
    for (int kp = 0; kp < 8; ++kp) {
        float4 q0 = p4[kp * 512 + t];
        float4 q1 = p4[kp * 512 + 256 + t];
        e0[2*kp].x = q0.x;   e0[2*kp].y = q0.y;
        e0[2*kp+1].x = q0.z; e0[2*kp+1].y = q0.w;
        e1[2*kp].x = q1.x;   e1[2*kp].y = q1.y;
        e1[2*kp+1].x = q1.z; e1[2*kp+1].y = q1.w;
    }
}

__device__ __forceinline__ void emb16_v2(const v2f (&x)[16],
                                         const float* __restrict__ W1, const float* __restrict__ b1,
                                         const float* __restrict__ W2, const float* __restrict__ b2,
                                         v2f (&e)[16]) {
    v2f h[16];
#pragma unroll
    for (int i = 0; i < 16; ++i) {
        v2f a = vbc(b1[i]);
#pragma unroll
        for (int k = 0; k < 16; ++k) a = vfma(W1[i * 16 + k], x[k], a);
        h[i] = vtanh(a);
    }
#pragma unroll
    for (int i = 0; i < 16; ++i) {
        v2f a = vbc(b2[i]);
#pragma unroll
        for (int k = 0; k < 16; ++k) a = vfma(W2[i * 16 + k], h[k], a);
        e[i] = vtanh(a);
    }
}

__device__ __forceinline__ v2f att_logit_v2(const v2f (&e)[16], const float (&qk)[16],
                                            const float* __restrict__ Wr,
                                            const float* __restrict__ V) {
    v2f acc = vbc(0.0f);
#pragma unroll
    for (int i = 0; i < 16; ++i) {
        v2f r = vbc(qk[i]);
#pragma unroll
        for (int k = 0; k < 16; ++k) r = vfma(Wr[i * 16 + k], e[k], r);
        acc = vfma2(vbc(V[i]), vtanh(r), acc);
    }
    return acc;
}

__device__ __forceinline__ float wave_reduce_sum(float v) {
#pragma unroll
    for (int off = 32; off > 0; off >>= 1) v += __shfl_xor(v, off, 64);
    return v;
}

__device__ __forceinline__ void wave_reduce_argmax(float &v, int &idx) {
#pragma unroll
    for (int off = 32; off > 0; off >>= 1) {
        float ov = __shfl_xor(v, off, 64);
        int oi = __shfl_xor(idx, off, 64);
        if (ov > v || (ov == v && oi < idx)) { v = ov; idx = oi; }
    }
}

__device__ __forceinline__ float block_sum(float v) {
    __shared__ float sm[4];
    v = wave_reduce_sum(v);
    __syncthreads();
    if ((threadIdx.x & 63) == 0) sm[threadIdx.x >> 6] = v;
    __syncthreads();
    return sm[0] + sm[1] + sm[2] + sm[3];
}

__device__ __forceinline__ void block_argmax(float &v, int &i) {
    __shared__ float sv[4];
    __shared__ int si[4];
    wave_reduce_argmax(v, i);
    __syncthreads();
    if ((threadIdx.x & 63) == 0) { sv[threadIdx.x >> 6] = v; si[threadIdx.x >> 6] = i; }
    __syncthreads();
    float bv = sv[0]; int bi = si[0];
#pragma unroll
    for (int k = 1; k < 4; ++k)
        if (sv[k] > bv || (sv[k] == bv && si[k] < bi)) { bv = sv[k]; bi = si[k]; }
    v = bv; i = bi;
}

// Block-reduce (l, s[16]) -> dst[17]. dst[0]=l, dst[1+j]=s[j]. Verified R7-R10.
__device__ __forceinline__ void block_sum17(float l, const float (&s)[16], float* dst) {
    const int lane = threadIdx.x & 63;
    float c[8];
#pragma unroll
    for (int j = 0; j < 8; ++j) {          // xor 1: 16 -> 8
        const bool hi = lane & 1;
        float t = __shfl_xor(hi ? s[j] : s[j + 8], 1, 64);
        c[j] = (hi ? s[j + 8] : s[j]) + t;
    }
    float d[4];
#pragma unroll
    for (int j = 0; j < 4; ++j) {          // xor 2: 8 -> 4
        const bool hi = lane & 2;
        float t = __shfl_xor(hi ? c[j] : c[j + 4], 2, 64);
        d[j] = (hi ? c[j + 4] : c[j]) + t;
    }
    float e2[2];
#pragma unroll
    for (int j = 0; j < 2; ++j) {          // xor 4: 4 -> 2
        const bool hi = lane & 4;
        float t = __shfl_xor(hi ? d[j] : d[j + 2], 4, 64);
        e2[j] = (hi ? d[j + 2] : d[j]) + t;
    }
    float f;
    {                                       // xor 8: 2 -> 1
        const bool hi = lane & 8;
        float t = __shfl_xor(hi ? e2[0] : e2[1], 8, 64);
        f = (hi ? e2[1] : e2[0]) + t;
    }
    f += __shfl_xor(f, 16, 64);
    f += __shfl_xor(f, 32, 64);
#pragma unroll
    for (int off = 32; off > 0; off >>= 1) l += __shfl_xor(l, off, 64);

    const int idx = ((lane & 1) << 3) | ((lane & 2) << 1) | ((lane & 4) >> 1) | ((lane & 8) >> 3);
    __shared__ float red[4][17];
    const int w = threadIdx.x >> 6;
    __syncthreads();                        // guard reuse across successive calls
    if (lane < 16) red[w][1 + idx] = f;
    if (lane == 0) red[w][0] = l;
    __syncthreads();
    if (threadIdx.x < 17)
        dst[threadIdx.x] = red[0][threadIdx.x] + red[1][threadIdx.x] + red[2][threadIdx.x] + red[3][threadIdx.x];
}

// weighted sum of 4 rows: s[i] = w01 . e0[i] + w23 . e1[i]
__device__ __forceinline__ void wsum4(const v2f (&e0)[16], const v2f (&e1)[16],
                                      v2f w01, v2f w23, float (&s)[16]) {
#pragma unroll
    for (int i = 0; i < 16; ++i) {
        v2f t = vfma2(w23, e1[i], w01 * e0[i]);
        s[i] = t.x + t.y;
    }
}

// ---------------------------------------------------------------------------
// redundant-prologue bodies (run by EVERY block of the consuming sweep;
// bit-identical results across blocks -> deterministic, race-free)
// ---------------------------------------------------------------------------

// P1 partials -> g(phase) -> qkout[16] (LDS). cvec = last_j (phase 0) or e_js.
__device__ __forceinline__ void combine_g_to(const Params& p, int phase,
                                             const float* cvec, float* qkout) {
    const float* PJ = p.S + P1J;
    const float* PM = p.S + P1M;
    float lJ = 0.0f, lM = 0.0f, sJ[16], sM[16];
#pragma unroll
    for (int c = 0; c < 16; ++c) { sJ[c] = 0.0f; sM[c] = 0.0f; }
    for (int i = threadIdx.x; i < GB_J; i += BLK) {
        lJ += PJ[i * 17];
#pragma unroll
        for (int c = 0; c < 16; ++c) sJ[c] += PJ[i * 17 + 1 + c];
    }
    for (int i = threadIdx.x; i < GB_M; i += BLK) {
        lM += PM[i * 17];
#pragma unroll
        for (int c = 0; c < 16; ++c) sM[c] += PM[i * 17 + 1 + c];
    }
    __shared__ float totJ[17], totM[17];
    block_sum17(lJ, sJ, totJ);
    block_sum17(lM, sM, totM);
    __syncthreads();

    __shared__ float cb[48], gbuf[16];
    if (threadIdx.x < 16) {
        int i = threadIdx.x;
        cb[i]      = cvec[i];
        cb[16 + i] = totJ[1 + i] / totJ[0];   // softmax-weighted sum / partition
        cb[32 + i] = totM[1 + i] / totM[0];
    }
    __syncthreads();
    const float* gW  = phase ? p.g2W : p.g1W;
    const float* gbv = phase ? p.g2b : p.g1b;
    if (threadIdx.x < 16) {
        int i = threadIdx.x;
        float a = gbv[i];
#pragma unroll
        for (int k = 0; k < 48; ++k) a = fmaf(gW[i * 48 + k], cb[k], a);
        gbuf[i] = fast_tanh(a);
    }
    __syncthreads();
    const float* Wq = phase ? p.ma_Wq : p.ja_Wq;
    const float* bq = phase ? p.ma_bq : p.ja_bq;
    if (threadIdx.x < 16) {
        int i = threadIdx.x;
        float a = bq[i];
#pragma unroll
        for (int k = 0; k < 16; ++k) a = fmaf(Wq[i * 16 + k], gbuf[k], a);
        qkout[i] = a;
    }
    __syncthreads();
}

// P2 partials -> sel_j, e_js (LDS eb[16]); optionally write S_LOGPJ/S_SELJ
// (identical values from every block -> benign redundant stores).
__device__ __forceinline__ void select_job(const Params& p, float* eb, bool writeLogp) {
    float v = -3.4e38f; int vi = 0x7fffffff; float l = 0.0f;
    for (int i = threadIdx.x; i < GB_J; i += BLK) {
        float pv = p.S[P2V + i];
        int pi = (int)p.S[P2I + i];
        if (pv > v || (pv == v && pi < vi)) { v = pv; vi = pi; }
        l += p.S[P2L + i];
    }
    l = block_sum(l);
    block_argmax(v, vi);
    const int sel = vi;

    __shared__ float xb[16], hb[16];
    if (threadIdx.x < 16) xb[threadIdx.x] = p.jobs[(size_t)sel * 16 + threadIdx.x];
    __syncthreads();
    if (threadIdx.x < 16) {
        int i = threadIdx.x;
        float a = p.jb1[i];
#pragma unroll
        for (int k = 0; k < 16; ++k) a = fmaf(p.jW1[i * 16 + k], xb[k], a);
        hb[i] = fast_tanh(a);
    }
    __syncthreads();
    if (threadIdx.x < 16) {
        int i = threadIdx.x;
        float a = p.jb2[i];
#pragma unroll
        for (int k = 0; k < 16; ++k) a = fmaf(p.jW2[i * 16 + k], hb[k], a);
        eb[i] = fast_tanh(a);
    }
    if (writeLogp && threadIdx.x == 0) {
        p.S[S_LOGPJ] = v - logf(l);     // log_softmax at the argmax
        p.S[S_SELJ] = (float)sel;
    }
    __syncthreads();
}

// ---------------------------------------------------------------------------
// K1: embeddings (cached to ws if CACHE) + glimpse-1 partial sums. (R10 as-is)
// ---------------------------------------------------------------------------
template <bool CACHE>
__global__ __launch_bounds__(BLK) void k_emb_g1(Params p) {
    const bool isJob = blockIdx.x < GB_J;
    const float* X  = isJob ? p.jobs : p.machines;
    const float* W1 = isJob ? p.jW1 : p.mW1;
    const float* b1 = isJob ? p.jb1 : p.mb1;
    const float* W2 = isJob ? p.jW2 : p.mW2;
    const float* b2 = isJob ? p.jb2 : p.mb2;
    const float* Wr = isJob ? p.aj_Wr : p.am_Wr;
    const float* V  = isJob ? p.aj_V  : p.am_V;
    float* E = isJob ? p.Ej : p.Em;
    const int n  = isJob ? NJ : NM;
    const int b0 = isJob ? (int)blockIdx.x : (int)blockIdx.x - GB_J;

    const int r0 = b0 * ROWS_PER_BLK + 4 * (int)threadIdx.x;
    const bool v = r0 < n;
    const size_t a0 = v ? (size_t)r0 : 0;
    const size_t d  = v ? 1 : 0;

    v2f x0[16], x1[16];
    load16_v2(X, a0, a0 + d, x0);
    load16_v2(X, a0 + 2 * d, a0 + 3 * d, x1);

    __shared__ float qks[16];
    if (threadIdx.x < 16) {
        const float* Wq = isJob ? p.aj_Wq : p.am_Wq;
        const float* bq = isJob ? p.aj_bq : p.am_bq;
        const int i = threadIdx.x;
        float a = bq[i];
#pragma unroll
        for (int k = 0; k < 16; ++k) a = fmaf(Wq[i * 16 + k], p.last_j[k], a);
        qks[i] = a;
    }
    __syncthreads();
    float qk[16];
#pragma unroll
    for (int i = 0; i < 16; ++i) qk[i] = qks[i];

    v2f e0[16], e1[16];
    emb16_v2(x0, W1, b1, W2, b2, e0);
    emb16_v2(x1, W1, b1, W2, b2, e1);
    if (CACHE) ecache_store4(E + (size_t)b0 * EBLK, (int)threadIdx.x, e0, e1);
    v2f lg0 = att_logit_v2(e0, qk, Wr, V);
    v2f lg1 = att_logit_v2(e1, qk, Wr, V);
    v2f w01, w23;
    w01.x = v ? __expf(lg0.x) : 0.0f;
    w01.y = v ? __expf(lg0.y) : 0.0f;
    w23.x = v ? __expf(lg1.x) : 0.0f;
    w23.y = v ? __expf(lg1.y) : 0.0f;
    float l = (w01.x + w01.y) + (w23.x + w23.y);
    float s[16];
    wsum4(e0, e1, w01, w23, s);

    block_sum17(l, s, p.S + (isJob ? P1J : P1M) + (size_t)b0 * 17);
}

// ---------------------------------------------------------------------------
// B': prologue = combine_g(0) -> qkJA (LDS); sweep job logits -> P2.
// ---------------------------------------------------------------------------
template <bool CACHE>
__global__ __launch_bounds__(BLK) void k_jlogits(Params p) {
    __shared__ float qkja[16];
    combine_g_to(p, 0, p.last_j, qkja);

    const int r0 = blockIdx.x * ROWS_PER_BLK + 4 * (int)threadIdx.x;
    const bool v = r0 < NJ;
    const size_t a0 = v ? (size_t)r0 : 0;
    const size_t d  = v ? 1 : 0;

    v2f e0[16], e1[16];
    if (CACHE) {
        ecache_load4(p.Ej + (size_t)blockIdx.x * EBLK, (int)threadIdx.x, e0, e1);
    } else {
        v2f x0[16], x1[16];
        load16_v2(p.jobs, a0, a0 + d, x0);
        load16_v2(p.jobs, a0 + 2 * d, a0 + 3 * d, x1);
        emb16_v2(x0, p.jW1, p.jb1, p.jW2, p.jb2, e0);
        emb16_v2(x1, p.jW1, p.jb1, p.jW2, p.jb2, e1);
    }
    float qk[16];
#pragma unroll
    for (int i = 0; i < 16; ++i) qk[i] = qkja[i];

    v2f lg0 = att_logit_v2(e0, qk, p.ja_Wr, p.ja_V);
    v2f lg1 = att_logit_v2(e1, qk, p.ja_Wr, p.ja_V);

    int4 mq = make_int4(0, 0, 0, 0);
    if (v) mq = *reinterpret_cast<const int4*>(p.mask + r0);
    const bool m0 = v && (mq.x != 0);
    const bool m1 = v && (mq.y != 0);
    const bool m2 = v && (mq.z != 0);
    const bool m3 = v && (mq.w != 0);
    float l = (m0 ? __expf(lg0.x) : 0.0f) + (m1 ? __expf(lg0.y) : 0.0f)
            + (m2 ? __expf(lg1.x) : 0.0f) + (m3 ? __expf(lg1.y) : 0.0f);
    float am0 = m0 ? lg0.x : NEGV - 1.0f;
    float am1 = m1 ? lg0.y : NEGV - 1.0f;
    float am2 = m2 ? lg1.x : NEGV - 1.0f;
    float am3 = m3 ? lg1.y : NEGV - 1.0f;
    float best = am0; int bi = r0;
    if (am1 > best) { best = am1; bi = r0 + 1; }
    if (am2 > best) { best = am2; bi = r0 + 2; }
    if (am3 > best) { best = am3; bi = r0 + 3; }

    l = wave_reduce_sum(l);
    wave_reduce_argmax(best, bi);
    __shared__ float rl[4], rv[4];
    __shared__ int ri[4];
    int w = threadIdx.x >> 6, ln = threadIdx.x & 63;
    if (ln == 0) { rl[w] = l; rv[w] = best; ri[w] = bi; }
    __syncthreads();
    if (threadIdx.x == 0) {
        float L = rl[0] + rl[1] + rl[2] + rl[3];
        float vv = rv[0]; int i = ri[0];
#pragma unroll
        for (int k = 1; k < 4; ++k)
            if (rv[k] > vv || (rv[k] == vv && ri[k] < i)) { vv = rv[k]; i = ri[k]; }
        p.S[P2V + blockIdx.x] = vv;
        p.S[P2I + blockIdx.x] = (float)i;   // exact: i < 2^24
        p.S[P2L + blockIdx.x] = L;
    }
}

// ---------------------------------------------------------------------------
// C': prologue = sel_j -> e_js -> qk2j/qk2m (LDS); sweep glimpse-2 -> P1.
// (reads P2, writes P1 -- disjoint, no intra-kernel hazard)
// ---------------------------------------------------------------------------
template <bool CACHE>
__global__ __launch_bounds__(BLK) void k_glimpse2(Params p) {
    __shared__ float eb[16], q2[32];
    select_job(p, eb, false);
    if (threadIdx.x < 16) {
        int i = threadIdx.x;
        float a1 = p.aj_bq[i], a2 = p.am_bq[i];
#pragma unroll
        for (int k = 0; k < 16; ++k) {
            a1 = fmaf(p.aj_Wq[i * 16 + k], eb[k], a1);
            a2 = fmaf(p.am_Wq[i * 16 + k], eb[k], a2);
        }
        q2[i] = a1;
        q2[16 + i] = a2;
    }
    __syncthreads();

    const bool isJob = blockIdx.x < GB_J;
    const float* Wr = isJob ? p.aj_Wr : p.am_Wr;
    const float* V  = isJob ? p.aj_V  : p.am_V;
    const float* E  = isJob ? p.Ej : p.Em;
    const float* X  = isJob ? p.jobs : p.machines;
    const float* W1 = isJob ? p.jW1 : p.mW1;
    const float* b1 = isJob ? p.jb1 : p.mb1;
    const float* W2 = isJob ? p.jW2 : p.mW2;
    const float* b2 = isJob ? p.jb2 : p.mb2;
    const int n  = isJob ? NJ : NM;
    const int b0 = isJob ? (int)blockIdx.x : (int)blockIdx.x - GB_J;

    float qk[16];
    {
        const float* qsrc = q2 + (isJob ? 0 : 16);
#pragma unroll
        for (int i = 0; i < 16; ++i) qk[i] = qsrc[i];
    }

    const int r0 = b0 * ROWS_PER_BLK + 4 * (int)threadIdx.x;
    const bool v = r0 < n;
    const size_t a0 = v ? (size_t)r0 : 0;
    const size_t d  = v ? 1 : 0;

    v2f e0[16], e1[16];
    if (CACHE) {
        ecache_load4(E + (size_t)b0 * EBLK, (int)threadIdx.x, e0, e1);
    } else {
        v2f x0[16], x1[16];
        load16_v2(X, a0, a0 + d, x0);
        load16_v2(X, a0 + 2 * d, a0 + 3 * d, x1);
        emb16_v2(x0, W1, b1, W2, b2, e0);
        emb16_v2(x1, W1, b1, W2, b2, e1);
    }
    v2f lg0 = att_logit_v2(e0, qk, Wr, V);
    v2f lg1 = att_logit_v2(e1, qk, Wr, V);
    v2f w01, w23;
    w01.x = v ? __expf(lg0.x) : 0.0f;
    w01.y = v ? __expf(lg0.y) : 0.0f;
    w23.x = v ? __expf(lg1.x) : 0.0f;
    w23.y = v ? __expf(lg1.y) : 0.0f;
    float l = (w01.x + w01.y) + (w23.x + w23.y);
    float s[16];
    wsum4(e0, e1, w01, w23, s);

    block_sum17(l, s, p.S + (isJob ? P1J : P1M) + (size_t)b0 * 17);
}

// ---------------------------------------------------------------------------
// D': prologue = sel_j/logp_j (from P2) + combine_g(1) with e_js (from P1)
//     -> qkMA (LDS); sweep machine logits -> P3 (NOT P2: prologue reads P2).
// ---------------------------------------------------------------------------
template <bool CACHE>
__global__ __launch_bounds__(BLK) void k_mlogits(Params p) {
    __shared__ float eb[16], qkma[16];
    select_job(p, eb, true);            // also writes S_LOGPJ/S_SELJ (identical per block)
    combine_g_to(p, 1, eb, qkma);

    const int r0 = blockIdx.x * ROWS_PER_BLK + 4 * (int)threadIdx.x;
    const bool v = r0 < NM;
    const size_t a0 = v ? (size_t)r0 : 0;
    const size_t d  = v ? 1 : 0;

    v2f e0[16], e1[16];
    if (CACHE) {
        ecache_load4(p.Em + (size_t)blockIdx.x * EBLK, (int)threadIdx.x, e0, e1);
    } else {
        v2f x0[16], x1[16];
        load16_v2(p.machines, a0, a0 + d, x0);
        load16_v2(p.machines, a0 + 2 * d, a0 + 3 * d, x1);
        emb16_v2(x0, p.mW1, p.mb1, p.mW2, p.mb2, e0);
        emb16_v2(x1, p.mW1, p.mb1, p.mW2, p.mb2, e1);
    }
    float qk[16];
#pragma unroll
    for (int i = 0; i < 16; ++i) qk[i] = qkma[i];

    v2f lg0 = att_logit_v2(e0, qk, p.ma_Wr, p.ma_V);
    v2f lg1 = att_logit_v2(e1, qk, p.ma_Wr, p.ma_V);
    float l = (v ? __expf(lg0.x) : 0.0f) + (v ? __expf(lg0.y) : 0.0f)
            + (v ? __expf(lg1.x) : 0.0f) + (v ? __expf(lg1.y) : 0.0f);
    float am0 = v ? lg0.x : -3.4e38f;
    float am1 = v ? lg0.y : -3.4e38f;
    float am2 = v ? lg1.x : -3.4e38f;
    float am3 = v ? lg1.y : -3.4e38f;
    float best = am0; int bi = r0;
    if (am1 > best) { best = am1; bi = r0 + 1; }
    if (am2 > best) { best = am2; bi = r0 + 2; }
    if (am3 > best) { best = am3; bi = r0 + 3; }

    l = wave_reduce_sum(l);
    wave_reduce_argmax(best, bi);
    __shared__ float rl[4], rv[4];
    __shared__ int ri[4];
    int w = threadIdx.x >> 6, ln = threadIdx.x & 63;
    if (ln == 0) { rl[w] = l; rv[w] = best; ri[w] = bi; }
    __syncthreads();
    if (threadIdx.x == 0) {
        float L = rl[0] + rl[1] + rl[2] + rl[3];
        float vv = rv[0]; int i = ri[0];
#pragma unroll
        for (int k = 1; k < 4; ++k)
            if (rv[k] > vv || (rv[k] == vv && ri[k] < i)) { vv = rv[k]; i = ri[k]; }
        p.S[P3V + blockIdx.x] = vv;
        p.S[P3I + blockIdx.x] = (float)i;
        p.S[P3L + blockIdx.x] = L;
    }
}

// ---------------------------------------------------------------------------
// C4: final combine over P3 -> outputs [sel_j, sel_m, logpas]
// ---------------------------------------------------------------------------
__global__ __launch_bounds__(BLK) void k_combine4(Params p) {
    float v = -3.4e38f; int vi = 0x7fffffff; float l = 0.0f;
    for (int i = threadIdx.x; i < GB_M; i += BLK) {
        float pv = p.S[P3V + i];
        int pi = (int)p.S[P3I + i];
        if (pv > v || (pv == v && pi < vi)) { v = pv; vi = pi; }
        l += p.S[P3L + i];
    }
    l = block_sum(l);
    block_argmax(v, vi);
    if (threadIdx.x == 0) {
        p.out[0] = p.S[S_SELJ];
        p.out[1] = (float)vi;
        p.out[2] = p.S[S_LOGPJ] + (v - logf(l));
    }
}

// ---------------------------------------------------------------------------
extern "C" void kernel_launch(void* const* d_in, const int* in_sizes, int n_in,
                              void* d_out, int out_size, void* d_ws, size_t ws_size,
                              hipStream_t stream) {
    Params p;
    p.jobs     = (const float*)d_in[0];
    p.machines = (const float*)d_in[1];
    p.mask     = (const int*)d_in[2];
    p.jW1 = (const float*)d_in[3];  p.jb1 = (const float*)d_in[4];
    p.jW2 = (const float*)d_in[5];  p.jb2 = (const float*)d_in[6];
    p.mW1 = (const float*)d_in[7];  p.mb1 = (const float*)d_in[8];
    p.mW2 = (const float*)d_in[9];  p.mb2 = (const float*)d_in[10];
    p.aj_Wq = (const float*)d_in[11]; p.aj_bq = (const float*)d_in[12];
    p.aj_Wr = (const float*)d_in[13]; p.aj_V  = (const float*)d_in[14];
    p.am_Wq = (const float*)d_in[15]; p.am_bq = (const float*)d_in[16];
    p.am_Wr = (const float*)d_in[17]; p.am_V  = (const float*)d_in[18];
    p.ja_Wq = (const float*)d_in[19]; p.ja_bq = (const float*)d_in[20];
    p.ja_Wr = (const float*)d_in[21]; p.ja_V  = (const float*)d_in[22];
    p.ma_Wq = (const float*)d_in[23]; p.ma_bq = (const float*)d_in[24];
    p.ma_Wr = (const float*)d_in[25]; p.ma_V  = (const float*)d_in[26];
    p.g1W = (const float*)d_in[27]; p.g1b = (const float*)d_in[28];
    p.g2W = (const float*)d_in[29]; p.g2b = (const float*)d_in[30];
    p.last_j = (const float*)d_in[31];
    p.S = (float*)d_ws;
    p.Ej = (float*)d_ws + E_OFF;
    p.Em = p.Ej + (size_t)GB_J * EBLK;
    p.out = (float*)d_out;

    const size_t needed = (E_OFF + (size_t)GB_TOT * EBLK) * sizeof(float);
    const bool cache = ws_size >= needed;

    if (cache) {
        k_emb_g1<true><<<GB_TOT, BLK, 0, stream>>>(p);
        k_jlogits<true><<<GB_J, BLK, 0, stream>>>(p);
        k_glimpse2<true><<<GB_TOT, BLK, 0, stream>>>(p);
        k_mlogits<true><<<GB_M, BLK, 0, stream>>>(p);
        k_combine4<<<1, BLK, 0, stream>>>(p);
    } else {
        k_emb_g1<false><<<GB_TOT, BLK, 0, stream>>>(p);
        k_jlogits<false><<<GB_J, BLK, 0, stream>>>(p);
        k_glimpse2<false><<<GB_TOT, BLK, 0, stream>>>(p);
        k_mlogits<false><<<GB_M, BLK, 0, stream>>>(p);
        k_combine4<<<1, BLK, 0, stream>>>(p);
    }
}

// Round 10
// 292.924 us; speedup vs baseline: 3.1665x; 1.0594x over previous
//
#include <hip/hip_runtime.h>
#include <cstddef>
#include <cstdint>

// ---------------------------------------------------------------------------
// attention_net_noc: pointer-network decode step.
// R13 = R10 (286.9 us best) with two local changes:
//  (1) Sweep A back to 2 rows/thread (grid 2932: packs 256 CUs at ~43% occ
//      vs 4-row's 26%), writing the SAME 4-row E-tile layout so downstream
//      4-row readers are untouched: pair q of a 1024-row tile -> slot
//      kp*512 + (q&1)*256 + (q>>1); q = half*256 + t.
//      Phase-0 partial counts double (2*GB_J / 2*GB_M); combine_g takes
//      per-phase counts.
//  (2) Nontemporal stores for the E-cache (written once, consumed via L3 by
//      later kernels; keeps A's L2 for its input stream).
// R12 lesson: combines+gaps are only ~6 us total; redundant per-block
// prologues cost ~25-30 us. R8/R11: cross-block sync (fences / coop barrier)
// poisons L2 on gfx950. Kernel boundaries are the cheap sync.
// ---------------------------------------------------------------------------

constexpr int NJ = 1000000;
constexpr int NM = 500000;
constexpr float NEGV = -1e8f;

constexpr int BLK = 256;
constexpr int ROWS_PER_BLK = 1024;           // downstream: 4 adjacent rows/thread
constexpr int GB_J = (NJ + ROWS_PER_BLK - 1) / ROWS_PER_BLK;   // 977 tiles
constexpr int GB_M = (NM + ROWS_PER_BLK - 1) / ROWS_PER_BLK;   // 489 tiles
constexpr int GB_TOT = GB_J + GB_M;                             // 1466
constexpr int EBLK = ROWS_PER_BLK * 16;                         // 16384 floats/tile

// Sweep A: 2 rows/thread, 2 blocks per tile (half = low/high 512 rows)
constexpr int GA_J = 2 * GB_J;               // 1954
constexpr int GA_M = 2 * GB_M;               // 978
constexpr int GA_TOT = GA_J + GA_M;          // 2932

// ---- workspace layout (float offsets from start of d_ws) ----
constexpr int S_QKJA = 0;    // 16: ja_Wq@g1 + ja_bq
constexpr int S_QK2J = 16;   // 16: aj_Wq@e_js + aj_bq
constexpr int S_QK2M = 32;   // 16: am_Wq@e_js + am_bq
constexpr int S_EJS  = 48;   // 16: E_j[sel_j]
constexpr int S_QKMA = 64;   // 16: ma_Wq@g2 + ma_bq
constexpr int S_LOGPJ = 80;
constexpr int S_SELJ  = 81;  // stored as float (exact, < 2^24)
constexpr int P1J = 128;                       // max(GA_J,GB_J)*17 glimpse partials
constexpr int P1M = P1J + GA_J * 17;           // max(GA_M,GB_M)*17
constexpr int P2V = P1M + GA_M * 17;           // GB_J argmax vals (mlogits reuses)
constexpr int P2I = P2V + GB_J;
constexpr int P2L = P2I + GB_J;
constexpr size_t E_OFF = 65536;                // float offset of E cache tiles
static_assert(P2L + GB_J <= (int)E_OFF, "partials overflow into E cache");
static_assert(NJ % 4 == 0 && NM % 4 == 0, "4-row packing needs n % 4 == 0");

typedef float v2f __attribute__((ext_vector_type(2)));
typedef float v4f __attribute__((ext_vector_type(4)));

struct Params {
    const float *jobs, *machines;
    const int *mask;
    const float *jW1, *jb1, *jW2, *jb2;
    const float *mW1, *mb1, *mW2, *mb2;
    const float *aj_Wq, *aj_bq, *aj_Wr, *aj_V;
    const float *am_Wq, *am_bq, *am_Wr, *am_V;
    const float *ja_Wq, *ja_bq, *ja_Wr, *ja_V;
    const float *ma_Wq, *ma_bq, *ma_Wr, *ma_V;
    const float *g1W, *g1b, *g2W, *g2b, *last_j;
    float *S;        // smalls + partials (in ws)
    float *Ej, *Em;  // embedding cache tiles (in ws; valid only if CACHE)
    float *out;
};

// ---------------------------------------------------------------------------
// device helpers (verified R9/R10 versions)
// ---------------------------------------------------------------------------

__device__ __forceinline__ float fast_tanh(float x) {
    float e = __builtin_amdgcn_exp2f(x * 2.8853900817779268f);  // 2/ln2
    float r = __builtin_amdgcn_rcpf(e + 1.0f);
    return fmaf(-2.0f, r, 1.0f);
}

__device__ __forceinline__ v2f vbc(float a) { v2f r; r.x = a; r.y = a; return r; }

__device__ __forceinline__ v2f vfma(float w, v2f b, v2f c) {
    return __builtin_elementwise_fma(vbc(w), b, c);
}
__device__ __forceinline__ v2f vfma2(v2f a, v2f b, v2f c) {
    return __builtin_elementwise_fma(a, b, c);
}
__device__ __forceinline__ v2f vtanh(v2f a) {
    v2f r; r.x = fast_tanh(a.x); r.y = fast_tanh(a.y); return r;
}

__device__ __forceinline__ void load16(const float* __restrict__ X, size_t r, float (&x)[16]) {
    const float4* p4 = reinterpret_cast<const float4*>(X) + r * 4;
    float4 a = p4[0], b = p4[1], c = p4[2], d = p4[3];
    x[0]=a.x; x[1]=a.y; x[2]=a.z; x[3]=a.w;
    x[4]=b.x; x[5]=b.y; x[6]=b.z; x[7]=b.w;
    x[8]=c.x; x[9]=c.y; x[10]=c.z; x[11]=c.w;
    x[12]=d.x; x[13]=d.y; x[14]=d.z; x[15]=d.w;
}

__device__ __forceinline__ void load16_v2(const float* __restrict__ X, size_t rA, size_t rB,
                                          v2f (&x)[16]) {
    float a[16], b[16];
    load16(X, rA, a);
    load16(X, rB, b);
#pragma unroll
    for (int k = 0; k < 16; ++k) { x[k].x = a[k]; x[k].y = b[k]; }
}

// 4-row tile layout: [8 kp][2 g][256] float4; pair q -> slot kp*512+(q&1)*256+(q>>1)
// A (2-row) store for pair q = half*256 + t, nontemporal:
__device__ __forceinline__ void ecache_store2(float* __restrict__ Eb, int t, int half,
                                              const v2f (&e)[16]) {
    v4f* p4 = reinterpret_cast<v4f*>(Eb);
    const int base = (t & 1) * 256 + half * 128 + (t >> 1);
#pragma unroll
    for (int kp = 0; kp < 8; ++kp) {
        v4f q;
        q.x = e[2*kp].x;   q.y = e[2*kp].y;
        q.z = e[2*kp+1].x; q.w = e[2*kp+1].y;
        __builtin_nontemporal_store(q, p4 + kp * 512 + base);
    }
}
// downstream (4-row) load: thread t owns pairs 2t (g=0) and 2t+1 (g=1)
__device__ __forceinline__ void ecache_load4(const float* __restrict__ Eb, int t,
                                             v2f (&e0)[16], v2f (&e1)[16]) {
    const float4* p4 = reinterpret_cast<const float4*>(Eb);
#pragma unroll
    for (int kp = 0; kp < 8; ++kp) {
        float4 q0 = p4[kp * 512 + t];
        float4 q1 = p4[kp * 512 + 256 + t];
        e0[2*kp].x = q0.x;   e0[2*kp].y = q0.y;
        e0[2*kp+1].x = q0.z; e0[2*kp+1].y = q0.w;
        e1[2*kp].x = q1.x;   e1[2*kp].y = q1.y;
        e1[2*kp+1].x = q1.z; e1[2*kp+1].y = q1.w;
    }
}

__device__ __forceinline__ void emb16_v2(const v2f (&x)[16],
                                         const float* __restrict__ W1, const float* __restrict__ b1,
                                         const float* __restrict__ W2, const float* __restrict__ b2,
                                         v2f (&e)[16]) {
    v2f h[16];
#pragma unroll
    for (int i = 0; i < 16; ++i) {
        v2f a = vbc(b1[i]);
#pragma unroll
        for (int k = 0; k < 16; ++k) a = vfma(W1[i * 16 + k], x[k], a);
        h[i] = vtanh(a);
    }
#pragma unroll
    for (int i = 0; i < 16; ++i) {
        v2f a = vbc(b2[i]);
#pragma unroll
        for (int k = 0; k < 16; ++k) a = vfma(W2[i * 16 + k], h[k], a);
        e[i] = vtanh(a);
    }
}

__device__ __forceinline__ v2f att_logit_v2(const v2f (&e)[16], const float (&qk)[16],
                                            const float* __restrict__ Wr,
                                            const float* __restrict__ V) {
    v2f acc = vbc(0.0f);
#pragma unroll
    for (int i = 0; i < 16; ++i) {
        v2f r = vbc(qk[i]);
#pragma unroll
        for (int k = 0; k < 16; ++k) r = vfma(Wr[i * 16 + k], e[k], r);
        acc = vfma2(vbc(V[i]), vtanh(r), acc);
    }
    return acc;
}

__device__ __forceinline__ float wave_reduce_sum(float v) {
#pragma unroll
    for (int off = 32; off > 0; off >>= 1) v += __shfl_xor(v, off, 64);
    return v;
}

__device__ __forceinline__ void wave_reduce_argmax(float &v, int &idx) {
#pragma unroll
    for (int off = 32; off > 0; off >>= 1) {
        float ov = __shfl_xor(v, off, 64);
        int oi = __shfl_xor(idx, off, 64);
        if (ov > v || (ov == v && oi < idx)) { v = ov; idx = oi; }
    }
}

__device__ __forceinline__ float block_sum(float v) {
    __shared__ float sm[4];
    v = wave_reduce_sum(v);
    __syncthreads();
    if ((threadIdx.x & 63) == 0) sm[threadIdx.x >> 6] = v;
    __syncthreads();
    return sm[0] + sm[1] + sm[2] + sm[3];
}

__device__ __forceinline__ void block_argmax(float &v, int &i) {
    __shared__ float sv[4];
    __shared__ int si[4];
    wave_reduce_argmax(v, i);
    __syncthreads();
    if ((threadIdx.x & 63) == 0) { sv[threadIdx.x >> 6] = v; si[threadIdx.x >> 6] = i; }
    __syncthreads();
    float bv = sv[0]; int bi = si[0];
#pragma unroll
    for (int k = 1; k < 4; ++k)
        if (sv[k] > bv || (sv[k] == bv && si[k] < bi)) { bv = sv[k]; bi = si[k]; }
    v = bv; i = bi;
}

// Block-reduce (l, s[16]) -> dst[17]. dst[0]=l, dst[1+j]=s[j]. Verified R7-R10.
__device__ __forceinline__ void block_sum17(float l, const float (&s)[16], float* dst) {
    const int lane = threadIdx.x & 63;
    float c[8];
#pragma unroll
    for (int j = 0; j < 8; ++j) {          // xor 1: 16 -> 8
        const bool hi = lane & 1;
        float t = __shfl_xor(hi ? s[j] : s[j + 8], 1, 64);
        c[j] = (hi ? s[j + 8] : s[j]) + t;
    }
    float d[4];
#pragma unroll
    for (int j = 0; j < 4; ++j) {          // xor 2: 8 -> 4
        const bool hi = lane & 2;
        float t = __shfl_xor(hi ? c[j] : c[j + 4], 2, 64);
        d[j] = (hi ? c[j + 4] : c[j]) + t;
    }
    float e2[2];
#pragma unroll
    for (int j = 0; j < 2; ++j) {          // xor 4: 4 -> 2
        const bool hi = lane & 4;
        float t = __shfl_xor(hi ? d[j] : d[j + 2], 4, 64);
        e2[j] = (hi ? d[j + 2] : d[j]) + t;
    }
    float f;
    {                                       // xor 8: 2 -> 1
        const bool hi = lane & 8;
        float t = __shfl_xor(hi ? e2[0] : e2[1], 8, 64);
        f = (hi ? e2[1] : e2[0]) + t;
    }
    f += __shfl_xor(f, 16, 64);
    f += __shfl_xor(f, 32, 64);
#pragma unroll
    for (int off = 32; off > 0; off >>= 1) l += __shfl_xor(l, off, 64);

    const int idx = ((lane & 1) << 3) | ((lane & 2) << 1) | ((lane & 4) >> 1) | ((lane & 8) >> 3);
    __shared__ float red[4][17];
    const int w = threadIdx.x >> 6;
    __syncthreads();                        // guard reuse across successive calls
    if (lane < 16) red[w][1 + idx] = f;
    if (lane == 0) red[w][0] = l;
    __syncthreads();
    if (threadIdx.x < 17)
        dst[threadIdx.x] = red[0][threadIdx.x] + red[1][threadIdx.x] + red[2][threadIdx.x] + red[3][threadIdx.x];
}

// weighted sum of 4 rows: s[i] = w01 . e0[i] + w23 . e1[i]
__device__ __forceinline__ void wsum4(const v2f (&e0)[16], const v2f (&e1)[16],
                                      v2f w01, v2f w23, float (&s)[16]) {
#pragma unroll
    for (int i = 0; i < 16; ++i) {
        v2f t = vfma2(w23, e1[i], w01 * e0[i]);
        s[i] = t.x + t.y;
    }
}

// ---------------------------------------------------------------------------
// K1 (sweep A): embeddings + glimpse-1 partials. 2 rows/thread, 2 blocks/tile.
// blocks [0,GA_J) -> jobs, [GA_J,GA_TOT) -> machines.
// ---------------------------------------------------------------------------
template <bool CACHE>
__global__ __launch_bounds__(BLK) void k_emb_g1(Params p) {
    const bool isJob = blockIdx.x < GA_J;
    const float* X  = isJob ? p.jobs : p.machines;
    const float* W1 = isJob ? p.jW1 : p.mW1;
    const float* b1 = isJob ? p.jb1 : p.mb1;
    const float* W2 = isJob ? p.jW2 : p.mW2;
    const float* b2 = isJob ? p.jb2 : p.mb2;
    const float* Wr = isJob ? p.aj_Wr : p.am_Wr;
    const float* V  = isJob ? p.aj_V  : p.am_V;
    float* E = isJob ? p.Ej : p.Em;
    const int n  = isJob ? NJ : NM;
    const int bb = isJob ? (int)blockIdx.x : (int)blockIdx.x - GA_J;
    const int tile = bb >> 1, half = bb & 1;

    const int r0 = tile * ROWS_PER_BLK + half * 512 + 2 * (int)threadIdx.x;
    const bool v = r0 < n;                 // n even => r0,r0+1 valid together
    const size_t a0 = v ? (size_t)r0 : 0;
    const size_t a1 = a0 + (v ? 1 : 0);

    v2f x[16];
    load16_v2(X, a0, a1, x);               // loads issue before prologue math

    __shared__ float qks[16];
    if (threadIdx.x < 16) {
        const float* Wq = isJob ? p.aj_Wq : p.am_Wq;
        const float* bq = isJob ? p.aj_bq : p.am_bq;
        const int i = threadIdx.x;
        float a = bq[i];
#pragma unroll
        for (int k = 0; k < 16; ++k) a = fmaf(Wq[i * 16 + k], p.last_j[k], a);
        qks[i] = a;
    }
    __syncthreads();
    float qk[16];
#pragma unroll
    for (int i = 0; i < 16; ++i) qk[i] = qks[i];

    v2f e[16];
    emb16_v2(x, W1, b1, W2, b2, e);
    if (CACHE) ecache_store2(E + (size_t)tile * EBLK, (int)threadIdx.x, half, e);
    v2f lg = att_logit_v2(e, qk, Wr, V);
    // |logit| <= sum|V| ~ 0.6 -> exp never overflows; no max-shift needed.
    float pw0 = v ? __expf(lg.x) : 0.0f;
    float pw1 = v ? __expf(lg.y) : 0.0f;
    float l = pw0 + pw1, s[16];
#pragma unroll
    for (int i = 0; i < 16; ++i) s[i] = fmaf(pw0, e[i].x, pw1 * e[i].y);

    block_sum17(l, s, p.S + (isJob ? P1J : P1M) + (size_t)bb * 17);
}

// ---------------------------------------------------------------------------
// Combine partials -> g (g1 or g2) -> next-stage qk vector. Single block.
// Phase 0 reads GA_* partials (sweep A); phase 1 reads GB_* (glimpse2).
// ---------------------------------------------------------------------------
__global__ __launch_bounds__(BLK) void k_combine_g(Params p, int phase) {
    const int nj = phase ? GB_J : GA_J;
    const int nm = phase ? GB_M : GA_M;
    const float* PJ = p.S + P1J;
    const float* PM = p.S + P1M;
    float lJ = 0.0f, lM = 0.0f, sJ[16], sM[16];
#pragma unroll
    for (int c = 0; c < 16; ++c) { sJ[c] = 0.0f; sM[c] = 0.0f; }
    for (int i = threadIdx.x; i < nj; i += BLK) {
        lJ += PJ[i * 17];
#pragma unroll
        for (int c = 0; c < 16; ++c) sJ[c] += PJ[i * 17 + 1 + c];
    }
    for (int i = threadIdx.x; i < nm; i += BLK) {
        lM += PM[i * 17];
#pragma unroll
        for (int c = 0; c < 16; ++c) sM[c] += PM[i * 17 + 1 + c];
    }
    __shared__ float totJ[17], totM[17];
    block_sum17(lJ, sJ, totJ);
    block_sum17(lM, sM, totM);
    __syncthreads();

    __shared__ float cb[48], gbuf[16];
    if (threadIdx.x < 16) {
        int i = threadIdx.x;
        cb[i]      = phase ? p.S[S_EJS + i] : p.last_j[i];
        cb[16 + i] = totJ[1 + i] / totJ[0];   // softmax-weighted sum / partition
        cb[32 + i] = totM[1 + i] / totM[0];
    }
    __syncthreads();
    const float* gW  = phase ? p.g2W : p.g1W;
    const float* gbv = phase ? p.g2b : p.g1b;
    if (threadIdx.x < 16) {
        int i = threadIdx.x;
        float a = gbv[i];
#pragma unroll
        for (int k = 0; k < 48; ++k) a = fmaf(gW[i * 48 + k], cb[k], a);
        gbuf[i] = fast_tanh(a);
    }
    __syncthreads();
    const float* Wq = phase ? p.ma_Wq : p.ja_Wq;
    const float* bq = phase ? p.ma_bq : p.ja_bq;
    const int off = phase ? S_QKMA : S_QKJA;
    if (threadIdx.x < 16) {
        int i = threadIdx.x;
        float a = bq[i];
#pragma unroll
        for (int k = 0; k < 16; ++k) a = fmaf(Wq[i * 16 + k], gbuf[k], a);
        p.S[off + i] = a;
    }
}

// ---------------------------------------------------------------------------
// K3: job pointer logits -> masked argmax + sum-exp partials. Rows (4t..4t+3).
// ---------------------------------------------------------------------------
template <bool CACHE>
__global__ __launch_bounds__(BLK) void k_jlogits(Params p) {
    const int r0 = blockIdx.x * ROWS_PER_BLK + 4 * (int)threadIdx.x;
    const bool v = r0 < NJ;
    const size_t a0 = v ? (size_t)r0 : 0;
    const size_t d  = v ? 1 : 0;

    v2f e0[16], e1[16];
    if (CACHE) {
        ecache_load4(p.Ej + (size_t)blockIdx.x * EBLK, (int)threadIdx.x, e0, e1);
    } else {
        v2f x0[16], x1[16];
        load16_v2(p.jobs, a0, a0 + d, x0);
        load16_v2(p.jobs, a0 + 2 * d, a0 + 3 * d, x1);
        emb16_v2(x0, p.jW1, p.jb1, p.jW2, p.jb2, e0);
        emb16_v2(x1, p.jW1, p.jb1, p.jW2, p.jb2, e1);
    }
    float qk[16];
#pragma unroll
    for (int i = 0; i < 16; ++i) qk[i] = p.S[S_QKJA + i];

    v2f lg0 = att_logit_v2(e0, qk, p.ja_Wr, p.ja_V);
    v2f lg1 = att_logit_v2(e1, qk, p.ja_Wr, p.ja_V);

    int4 mq = make_int4(0, 0, 0, 0);
    if (v) mq = *reinterpret_cast<const int4*>(p.mask + r0);   // r0 mult of 4 -> 16B aligned
    const bool m0 = v && (mq.x != 0);
    const bool m1 = v && (mq.y != 0);
    const bool m2 = v && (mq.z != 0);
    const bool m3 = v && (mq.w != 0);
    float l = (m0 ? __expf(lg0.x) : 0.0f) + (m1 ? __expf(lg0.y) : 0.0f)
            + (m2 ? __expf(lg1.x) : 0.0f) + (m3 ? __expf(lg1.y) : 0.0f);
    float am0 = m0 ? lg0.x : NEGV - 1.0f;  // invalid rows below masked NEG
    float am1 = m1 ? lg0.y : NEGV - 1.0f;
    float am2 = m2 ? lg1.x : NEGV - 1.0f;
    float am3 = m3 ? lg1.y : NEGV - 1.0f;
    float best = am0; int bi = r0;
    if (am1 > best) { best = am1; bi = r0 + 1; }
    if (am2 > best) { best = am2; bi = r0 + 2; }
    if (am3 > best) { best = am3; bi = r0 + 3; }

    l = wave_reduce_sum(l);
    wave_reduce_argmax(best, bi);
    __shared__ float rl[4], rv[4];
    __shared__ int ri[4];
    int w = threadIdx.x >> 6, ln = threadIdx.x & 63;
    if (ln == 0) { rl[w] = l; rv[w] = best; ri[w] = bi; }
    __syncthreads();
    if (threadIdx.x == 0) {
        float L = rl[0] + rl[1] + rl[2] + rl[3];
        float vv = rv[0]; int i = ri[0];
#pragma unroll
        for (int k = 1; k < 4; ++k)
            if (rv[k] > vv || (rv[k] == vv && ri[k] < i)) { vv = rv[k]; i = ri[k]; }
        p.S[P2V + blockIdx.x] = vv;
        p.S[P2I + blockIdx.x] = (float)i;   // exact: i < 2^24
        p.S[P2L + blockIdx.x] = L;
    }
}

// ---------------------------------------------------------------------------
// C2: global argmax over job logits; logp_j; e_js = emb(jobs[sel_j]); qk2j/qk2m
// ---------------------------------------------------------------------------
__global__ __launch_bounds__(BLK) void k_combine2(Params p) {
    float v = -3.4e38f; int vi = 0x7fffffff; float l = 0.0f;
    for (int i = threadIdx.x; i < GB_J; i += BLK) {
        float pv = p.S[P2V + i];
        int pi = (int)p.S[P2I + i];
        if (pv > v || (pv == v && pi < vi)) { v = pv; vi = pi; }
        l += p.S[P2L + i];
    }
    l = block_sum(l);
    block_argmax(v, vi);
    const int sel = vi;

    __shared__ float xb[16], hb[16], eb[16];
    if (threadIdx.x < 16) xb[threadIdx.x] = p.jobs[(size_t)sel * 16 + threadIdx.x];
    __syncthreads();
    if (threadIdx.x < 16) {
        int i = threadIdx.x;
        float a = p.jb1[i];
#pragma unroll
        for (int k = 0; k < 16; ++k) a = fmaf(p.jW1[i * 16 + k], xb[k], a);
        hb[i] = fast_tanh(a);
    }
    __syncthreads();
    if (threadIdx.x < 16) {
        int i = threadIdx.x;
        float a = p.jb2[i];
#pragma unroll
        for (int k = 0; k < 16; ++k) a = fmaf(p.jW2[i * 16 + k], hb[k], a);
        float e = fast_tanh(a);
        eb[i] = e;
        p.S[S_EJS + i] = e;
    }
    __syncthreads();
    if (threadIdx.x < 16) {
        int i = threadIdx.x;
        float a1 = p.aj_bq[i], a2 = p.am_bq[i];
#pragma unroll
        for (int k = 0; k < 16; ++k) {
            a1 = fmaf(p.aj_Wq[i * 16 + k], eb[k], a1);
            a2 = fmaf(p.am_Wq[i * 16 + k], eb[k], a2);
        }
        p.S[S_QK2J + i] = a1;
        p.S[S_QK2M + i] = a2;
    }
    if (threadIdx.x == 0) {
        p.S[S_LOGPJ] = v - logf(l);     // log_softmax at the argmax
        p.S[S_SELJ] = (float)sel;
    }
}

// ---------------------------------------------------------------------------
// K4: glimpse-2 over jobs (aj_*) and machines (am_*), query e_js. Rows (4t..4t+3).
// Writes partials into the (already consumed) P1 buffers (GB_* counts).
// ---------------------------------------------------------------------------
template <bool CACHE>
__global__ __launch_bounds__(BLK) void k_glimpse2(Params p) {
    const bool isJob = blockIdx.x < GB_J;
    const float* Wr = isJob ? p.aj_Wr : p.am_Wr;
    const float* V  = isJob ? p.aj_V  : p.am_V;
    const float* E  = isJob ? p.Ej : p.Em;
    const float* X  = isJob ? p.jobs : p.machines;
    const float* W1 = isJob ? p.jW1 : p.mW1;
    const float* b1 = isJob ? p.jb1 : p.mb1;
    const float* W2 = isJob ? p.jW2 : p.mW2;
    const float* b2 = isJob ? p.jb2 : p.mb2;
    const int n  = isJob ? NJ : NM;
    const int b0 = isJob ? (int)blockIdx.x : (int)blockIdx.x - GB_J;
    const int qoff = isJob ? S_QK2J : S_QK2M;

    const int r0 = b0 * ROWS_PER_BLK + 4 * (int)threadIdx.x;
    const bool v = r0 < n;
    const size_t a0 = v ? (size_t)r0 : 0;
    const size_t d  = v ? 1 : 0;

    v2f e0[16], e1[16];
    if (CACHE) {
        ecache_load4(E + (size_t)b0 * EBLK, (int)threadIdx.x, e0, e1);
    } else {
        v2f x0[16], x1[16];
        load16_v2(X, a0, a0 + d, x0);
        load16_v2(X, a0 + 2 * d, a0 + 3 * d, x1);
        emb16_v2(x0, W1, b1, W2, b2, e0);
        emb16_v2(x1, W1, b1, W2, b2, e1);
    }
    float qk[16];
#pragma unroll
    for (int i = 0; i < 16; ++i) qk[i] = p.S[qoff + i];

    v2f lg0 = att_logit_v2(e0, qk, Wr, V);
    v2f lg1 = att_logit_v2(e1, qk, Wr, V);
    v2f w01, w23;
    w01.x = v ? __expf(lg0.x) : 0.0f;
    w01.y = v ? __expf(lg0.y) : 0.0f;
    w23.x = v ? __expf(lg1.x) : 0.0f;
    w23.y = v ? __expf(lg1.y) : 0.0f;
    float l = (w01.x + w01.y) + (w23.x + w23.y);
    float s[16];
    wsum4(e0, e1, w01, w23, s);

    block_sum17(l, s, p.S + (isJob ? P1J : P1M) + (size_t)b0 * 17);
}

// ---------------------------------------------------------------------------
// K5: machine logits -> argmax + sum-exp partials. Rows (4t..4t+3).
// Writes into the (already consumed) P2 buffers.
// ---------------------------------------------------------------------------
template <bool CACHE>
__global__ __launch_bounds__(BLK) void k_mlogits(Params p) {
    const int r0 = blockIdx.x * ROWS_PER_BLK + 4 * (int)threadIdx.x;
    const bool v = r0 < NM;
    const size_t a0 = v ? (size_t)r0 : 0;
    const size_t d  = v ? 1 : 0;

    v2f e0[16], e1[16];
    if (CACHE) {
        ecache_load4(p.Em + (size_t)blockIdx.x * EBLK, (int)threadIdx.x, e0, e1);
    } else {
        v2f x0[16], x1[16];
        load16_v2(p.machines, a0, a0 + d, x0);
        load16_v2(p.machines, a0 + 2 * d, a0 + 3 * d, x1);
        emb16_v2(x0, p.mW1, p.mb1, p.mW2, p.mb2, e0);
        emb16_v2(x1, p.mW1, p.mb1, p.mW2, p.mb2, e1);
    }
    float qk[16];
#pragma unroll
    for (int i = 0; i < 16; ++i) qk[i] = p.S[S_QKMA + i];

    v2f lg0 = att_logit_v2(e0, qk, p.ma_Wr, p.ma_V);
    v2f lg1 = att_logit_v2(e1, qk, p.ma_Wr, p.ma_V);
    float l = (v ? __expf(lg0.x) : 0.0f) + (v ? __expf(lg0.y) : 0.0f)
            + (v ? __expf(lg1.x) : 0.0f) + (v ? __expf(lg1.y) : 0.0f);
    float am0 = v ? lg0.x : -3.4e38f;
    float am1 = v ? lg0.y : -3.4e38f;
    float am2 = v ? lg1.x : -3.4e38f;
    float am3 = v ? lg1.y : -3.4e38f;
    float best = am0; int bi = r0;
    if (am1 > best) { best = am1; bi = r0 + 1; }
    if (am2 > best) { best = am2; bi = r0 + 2; }
    if (am3 > best) { best = am3; bi = r0 + 3; }

    l = wave_reduce_sum(l);
    wave_reduce_argmax(best, bi);
    __shared__ float rl[4], rv[4];
    __shared__ int ri[4];
    int w = threadIdx.x >> 6, ln = threadIdx.x & 63;
    if (ln == 0) { rl[w] = l; rv[w] = best; ri[w] = bi; }
    __syncthreads();
    if (threadIdx.x == 0) {
        float L = rl[0] + rl[1] + rl[2] + rl[3];
        float vv = rv[0]; int i = ri[0];
#pragma unroll
        for (int k = 1; k < 4; ++k)
            if (rv[k] > vv || (rv[k] == vv && ri[k] < i)) { vv = rv[k]; i = ri[k]; }
        p.S[P2V + blockIdx.x] = vv;
        p.S[P2I + blockIdx.x] = (float)i;
        p.S[P2L + blockIdx.x] = L;
    }
}

// ---------------------------------------------------------------------------
// C4: final combine -> outputs [sel_j, sel_m, logpas] as float32
// ---------------------------------------------------------------------------
__global__ __launch_bounds__(BLK) void k_combine4(Params p) {
    float v = -3.4e38f; int vi = 0x7fffffff; float l = 0.0f;
    for (int i = threadIdx.x; i < GB_M; i += BLK) {
        float pv = p.S[P2V + i];
        int pi = (int)p.S[P2I + i];
        if (pv > v || (pv == v && pi < vi)) { v = pv; vi = pi; }
        l += p.S[P2L + i];
    }
    l = block_sum(l);
    block_argmax(v, vi);
    if (threadIdx.x == 0) {
        p.out[0] = p.S[S_SELJ];
        p.out[1] = (float)vi;
        p.out[2] = p.S[S_LOGPJ] + (v - logf(l));
    }
}

// ---------------------------------------------------------------------------
extern "C" void kernel_launch(void* const* d_in, const int* in_sizes, int n_in,
                              void* d_out, int out_size, void* d_ws, size_t ws_size,
                              hipStream_t stream) {
    Params p;
    p.jobs     = (const float*)d_in[0];
    p.machines = (const float*)d_in[1];
    p.mask     = (const int*)d_in[2];
    p.jW1 = (const float*)d_in[3];  p.jb1 = (const float*)d_in[4];
    p.jW2 = (const float*)d_in[5];  p.jb2 = (const float*)d_in[6];
    p.mW1 = (const float*)d_in[7];  p.mb1 = (const float*)d_in[8];
    p.mW2 = (const float*)d_in[9];  p.mb2 = (const float*)d_in[10];
    p.aj_Wq = (const float*)d_in[11]; p.aj_bq = (const float*)d_in[12];
    p.aj_Wr = (const float*)d_in[13]; p.aj_V  = (const float*)d_in[14];
    p.am_Wq = (const float*)d_in[15]; p.am_bq = (const float*)d_in[16];
    p.am_Wr = (const float*)d_in[17]; p.am_V  = (const float*)d_in[18];
    p.ja_Wq = (const float*)d_in[19]; p.ja_bq = (const float*)d_in[20];
    p.ja_Wr = (const float*)d_in[21]; p.ja_V  = (const float*)d_in[22];
    p.ma_Wq = (const float*)d_in[23]; p.ma_bq = (const float*)d_in[24];
    p.ma_Wr = (const float*)d_in[25]; p.ma_V  = (const float*)d_in[26];
    p.g1W = (const float*)d_in[27]; p.g1b = (const float*)d_in[28];
    p.g2W = (const float*)d_in[29]; p.g2b = (const float*)d_in[30];
    p.last_j = (const float*)d_in[31];
    p.S = (float*)d_ws;
    p.Ej = (float*)d_ws + E_OFF;
    p.Em = p.Ej + (size_t)GB_J * EBLK;
    p.out = (float*)d_out;

    const size_t needed = (E_OFF + (size_t)GB_TOT * EBLK) * sizeof(float);
    const bool cache = ws_size >= needed;

    if (cache) {
        k_emb_g1<true><<<GA_TOT, BLK, 0, stream>>>(p);
        k_combine_g<<<1, BLK, 0, stream>>>(p, 0);
        k_jlogits<true><<<GB_J, BLK, 0, stream>>>(p);
        k_combine2<<<1, BLK, 0, stream>>>(p);
        k_glimpse2<true><<<GB_TOT, BLK, 0, stream>>>(p);
        k_combine_g<<<1, BLK, 0, stream>>>(p, 1);
        k_mlogits<true><<<GB_M, BLK, 0, stream>>>(p);
        k_combine4<<<1, BLK, 0, stream>>>(p);
    } else {
        k_emb_g1<false><<<GA_TOT, BLK, 0, stream>>>(p);
        k_combine_g<<<1, BLK, 0, stream>>>(p, 0);
        k_jlogits<false><<<GB_J, BLK, 0, stream>>>(p);
        k_combine2<<<1, BLK, 0, stream>>>(p);
        k_glimpse2<false><<<GB_TOT, BLK, 0, stream>>>(p);
        k_combine_g<<<1, BLK, 0, stream>>>(p, 1);
        k_mlogits<false><<<GB_M, BLK, 0, stream>>>(p);
        k_combine4<<<1, BLK, 0, stream>>>(p);
    }
}

// Round 11
// 282.549 us; speedup vs baseline: 3.2828x; 1.0367x over previous
//
#include <hip/hip_runtime.h>
#include <cstddef>
#include <cstdint>

// ---------------------------------------------------------------------------
// attention_net_noc: pointer-network decode step.
// R14 = exact R10 structure (286.9 us, session best) + issue-order micros:
//   - k_jlogits: mask int4 load issued BEFORE the E-cache loads (in flight
//     together; was issued after ~700 VALU slots of logit math).
// Plateau ledger (13 rounds):
//   A ~70us (VALU 45%/HBM 26%, neither saturated); B+C+D ~200us latency-bound
//   L3 reads (BW floor would be ~27us); combines+gaps ~6us (R12 delta).
//   Dead ends measured on gfx950: ticket fences (R8, 6x), cooperative grid
//   barriers (R11, 3.2x + 911MB HBM), redundant combine prologues (R12, +23us),
//   A-occupancy repack + NT stores (R13, +6us). bf16 E-cache rejected:
//   ~2e-3 logit noise vs ~3e-2 top-2 gap -> O(10%) argmax-flip risk.
// ---------------------------------------------------------------------------

constexpr int NJ = 1000000;
constexpr int NM = 500000;
constexpr float NEGV = -1e8f;

constexpr int BLK = 256;
constexpr int ROWS_PER_BLK = 1024;           // 4 adjacent rows per thread
constexpr int GB_J = (NJ + ROWS_PER_BLK - 1) / ROWS_PER_BLK;   // 977
constexpr int GB_M = (NM + ROWS_PER_BLK - 1) / ROWS_PER_BLK;   // 489
constexpr int GB_TOT = GB_J + GB_M;                             // 1466
constexpr int EBLK = ROWS_PER_BLK * 16;                         // 16384 floats/tile

// ---- workspace layout (float offsets from start of d_ws) ----
constexpr int S_QKJA = 0;    // 16: ja_Wq@g1 + ja_bq
constexpr int S_QK2J = 16;   // 16: aj_Wq@e_js + aj_bq
constexpr int S_QK2M = 32;   // 16: am_Wq@e_js + am_bq
constexpr int S_EJS  = 48;   // 16: E_j[sel_j]
constexpr int S_QKMA = 64;   // 16: ma_Wq@g2 + ma_bq
constexpr int S_LOGPJ = 80;
constexpr int S_SELJ  = 81;  // stored as float (exact, < 2^24)
constexpr int P1J = 128;                       // GB_J*17 glimpse partials (l, s[16])
constexpr int P1M = P1J + GB_J * 17;
constexpr int P2V = P1M + GB_M * 17;           // GB_J argmax vals (mlogits reuses)
constexpr int P2I = P2V + GB_J;
constexpr int P2L = P2I + GB_J;
constexpr size_t E_OFF = 65536;                // float offset of E cache tiles
static_assert(P2L + GB_J <= (int)E_OFF, "partials overflow into E cache");
static_assert(NJ % 4 == 0 && NM % 4 == 0, "4-row packing needs n % 4 == 0");

typedef float v2f __attribute__((ext_vector_type(2)));

struct Params {
    const float *jobs, *machines;
    const int *mask;
    const float *jW1, *jb1, *jW2, *jb2;
    const float *mW1, *mb1, *mW2, *mb2;
    const float *aj_Wq, *aj_bq, *aj_Wr, *aj_V;
    const float *am_Wq, *am_bq, *am_Wr, *am_V;
    const float *ja_Wq, *ja_bq, *ja_Wr, *ja_V;
    const float *ma_Wq, *ma_bq, *ma_Wr, *ma_V;
    const float *g1W, *g1b, *g2W, *g2b, *last_j;
    float *S;        // smalls + partials (in ws)
    float *Ej, *Em;  // embedding cache tiles (in ws; valid only if CACHE)
    float *out;
};

// ---------------------------------------------------------------------------
// device helpers (verified R9/R10 versions, unchanged)
// ---------------------------------------------------------------------------

__device__ __forceinline__ float fast_tanh(float x) {
    float e = __builtin_amdgcn_exp2f(x * 2.8853900817779268f);  // 2/ln2
    float r = __builtin_amdgcn_rcpf(e + 1.0f);
    return fmaf(-2.0f, r, 1.0f);
}

__device__ __forceinline__ v2f vbc(float a) { v2f r; r.x = a; r.y = a; return r; }

__device__ __forceinline__ v2f vfma(float w, v2f b, v2f c) {
    return __builtin_elementwise_fma(vbc(w), b, c);
}
__device__ __forceinline__ v2f vfma2(v2f a, v2f b, v2f c) {
    return __builtin_elementwise_fma(a, b, c);
}
__device__ __forceinline__ v2f vtanh(v2f a) {
    v2f r; r.x = fast_tanh(a.x); r.y = fast_tanh(a.y); return r;
}

__device__ __forceinline__ void load16(const float* __restrict__ X, size_t r, float (&x)[16]) {
    const float4* p4 = reinterpret_cast<const float4*>(X) + r * 4;
    float4 a = p4[0], b = p4[1], c = p4[2], d = p4[3];
    x[0]=a.x; x[1]=a.y; x[2]=a.z; x[3]=a.w;
    x[4]=b.x; x[5]=b.y; x[6]=b.z; x[7]=b.w;
    x[8]=c.x; x[9]=c.y; x[10]=c.z; x[11]=c.w;
    x[12]=d.x; x[13]=d.y; x[14]=d.z; x[15]=d.w;
}

__device__ __forceinline__ void load16_v2(const float* __restrict__ X, size_t rA, size_t rB,
                                          v2f (&x)[16]) {
    float a[16], b[16];
    load16(X, rA, a);
    load16(X, rB, b);
#pragma unroll
    for (int k = 0; k < 16; ++k) { x[k].x = a[k]; x[k].y = b[k]; }
}

// E-cache tile for 4 rows/thread: [8][2 pairs][256 threads * float4].
__device__ __forceinline__ void ecache_store4(float* __restrict__ Eb, int t,
                                              const v2f (&e0)[16], const v2f (&e1)[16]) {
    float4* p4 = reinterpret_cast<float4*>(Eb);
#pragma unroll
    for (int kp = 0; kp < 8; ++kp) {
        p4[kp * 512 + t]       = make_float4(e0[2*kp].x, e0[2*kp].y, e0[2*kp+1].x, e0[2*kp+1].y);
        p4[kp * 512 + 256 + t] = make_float4(e1[2*kp].x, e1[2*kp].y, e1[2*kp+1].x, e1[2*kp+1].y);
    }
}
__device__ __forceinline__ void ecache_load4(const float* __restrict__ Eb, int t,
                                             v2f (&e0)[16], v2f (&e1)[16]) {
    const float4* p4 = reinterpret_cast<const float4*>(Eb);
#pragma unroll
    for (int kp = 0; kp < 8; ++kp) {
        float4 q0 = p4[kp * 512 + t];
        float4 q1 = p4[kp * 512 + 256 + t];
        e0[2*kp].x = q0.x;   e0[2*kp].y = q0.y;
        e0[2*kp+1].x = q0.z; e0[2*kp+1].y = q0.w;
        e1[2*kp].x = q1.x;   e1[2*kp].y = q1.y;
        e1[2*kp+1].x = q1.z; e1[2*kp+1].y = q1.w;
    }
}

__device__ __forceinline__ void emb16_v2(const v2f (&x)[16],
                                         const float* __restrict__ W1, const float* __restrict__ b1,
                                         const float* __restrict__ W2, const float* __restrict__ b2,
                                         v2f (&e)[16]) {
    v2f h[16];
#pragma unroll
    for (int i = 0; i < 16; ++i) {
        v2f a = vbc(b1[i]);
#pragma unroll
        for (int k = 0; k < 16; ++k) a = vfma(W1[i * 16 + k], x[k], a);
        h[i] = vtanh(a);
    }
#pragma unroll
    for (int i = 0; i < 16; ++i) {
        v2f a = vbc(b2[i]);
#pragma unroll
        for (int k = 0; k < 16; ++k) a = vfma(W2[i * 16 + k], h[k], a);
        e[i] = vtanh(a);
    }
}

__device__ __forceinline__ v2f att_logit_v2(const v2f (&e)[16], const float (&qk)[16],
                                            const float* __restrict__ Wr,
                                            const float* __restrict__ V) {
    v2f acc = vbc(0.0f);
#pragma unroll
    for (int i = 0; i < 16; ++i) {
        v2f r = vbc(qk[i]);
#pragma unroll
        for (int k = 0; k < 16; ++k) r = vfma(Wr[i * 16 + k], e[k], r);
        acc = vfma2(vbc(V[i]), vtanh(r), acc);
    }
    return acc;
}

__device__ __forceinline__ float wave_reduce_sum(float v) {
#pragma unroll
    for (int off = 32; off > 0; off >>= 1) v += __shfl_xor(v, off, 64);
    return v;
}

__device__ __forceinline__ void wave_reduce_argmax(float &v, int &idx) {
#pragma unroll
    for (int off = 32; off > 0; off >>= 1) {
        float ov = __shfl_xor(v, off, 64);
        int oi = __shfl_xor(idx, off, 64);
        if (ov > v || (ov == v && oi < idx)) { v = ov; idx = oi; }
    }
}

__device__ __forceinline__ float block_sum(float v) {
    __shared__ float sm[4];
    v = wave_reduce_sum(v);
    __syncthreads();
    if ((threadIdx.x & 63) == 0) sm[threadIdx.x >> 6] = v;
    __syncthreads();
    return sm[0] + sm[1] + sm[2] + sm[3];
}

__device__ __forceinline__ void block_argmax(float &v, int &i) {
    __shared__ float sv[4];
    __shared__ int si[4];
    wave_reduce_argmax(v, i);
    __syncthreads();
    if ((threadIdx.x & 63) == 0) { sv[threadIdx.x >> 6] = v; si[threadIdx.x >> 6] = i; }
    __syncthreads();
    float bv = sv[0]; int bi = si[0];
#pragma unroll
    for (int k = 1; k < 4; ++k)
        if (sv[k] > bv || (sv[k] == bv && si[k] < bi)) { bv = sv[k]; bi = si[k]; }
    v = bv; i = bi;
}

// Block-reduce (l, s[16]) -> dst[17]. dst[0]=l, dst[1+j]=s[j]. Verified R7-R13.
__device__ __forceinline__ void block_sum17(float l, const float (&s)[16], float* dst) {
    const int lane = threadIdx.x & 63;
    float c[8];
#pragma unroll
    for (int j = 0; j < 8; ++j) {          // xor 1: 16 -> 8
        const bool hi = lane & 1;
        float t = __shfl_xor(hi ? s[j] : s[j + 8], 1, 64);
        c[j] = (hi ? s[j + 8] : s[j]) + t;
    }
    float d[4];
#pragma unroll
    for (int j = 0; j < 4; ++j) {          // xor 2: 8 -> 4
        const bool hi = lane & 2;
        float t = __shfl_xor(hi ? c[j] : c[j + 4], 2, 64);
        d[j] = (hi ? c[j + 4] : c[j]) + t;
    }
    float e2[2];
#pragma unroll
    for (int j = 0; j < 2; ++j) {          // xor 4: 4 -> 2
        const bool hi = lane & 4;
        float t = __shfl_xor(hi ? d[j] : d[j + 2], 4, 64);
        e2[j] = (hi ? d[j + 2] : d[j]) + t;
    }
    float f;
    {                                       // xor 8: 2 -> 1
        const bool hi = lane & 8;
        float t = __shfl_xor(hi ? e2[0] : e2[1], 8, 64);
        f = (hi ? e2[1] : e2[0]) + t;
    }
    f += __shfl_xor(f, 16, 64);
    f += __shfl_xor(f, 32, 64);
#pragma unroll
    for (int off = 32; off > 0; off >>= 1) l += __shfl_xor(l, off, 64);

    const int idx = ((lane & 1) << 3) | ((lane & 2) << 1) | ((lane & 4) >> 1) | ((lane & 8) >> 3);
    __shared__ float red[4][17];
    const int w = threadIdx.x >> 6;
    __syncthreads();                        // guard reuse across successive calls
    if (lane < 16) red[w][1 + idx] = f;
    if (lane == 0) red[w][0] = l;
    __syncthreads();
    if (threadIdx.x < 17)
        dst[threadIdx.x] = red[0][threadIdx.x] + red[1][threadIdx.x] + red[2][threadIdx.x] + red[3][threadIdx.x];
}

// weighted sum of 4 rows: s[i] = w01 . e0[i] + w23 . e1[i]
__device__ __forceinline__ void wsum4(const v2f (&e0)[16], const v2f (&e1)[16],
                                      v2f w01, v2f w23, float (&s)[16]) {
#pragma unroll
    for (int i = 0; i < 16; ++i) {
        v2f t = vfma2(w23, e1[i], w01 * e0[i]);
        s[i] = t.x + t.y;
    }
}

// ---------------------------------------------------------------------------
// K1: embeddings (cached to ws if CACHE) + glimpse-1 partial sums. Rows (4t..4t+3).
// blocks [0,GB_J) -> jobs, [GB_J,GB_TOT) -> machines.
// ---------------------------------------------------------------------------
template <bool CACHE>
__global__ __launch_bounds__(BLK) void k_emb_g1(Params p) {
    const bool isJob = blockIdx.x < GB_J;
    const float* X  = isJob ? p.jobs : p.machines;
    const float* W1 = isJob ? p.jW1 : p.mW1;
    const float* b1 = isJob ? p.jb1 : p.mb1;
    const float* W2 = isJob ? p.jW2 : p.mW2;
    const float* b2 = isJob ? p.jb2 : p.mb2;
    const float* Wr = isJob ? p.aj_Wr : p.am_Wr;
    const float* V  = isJob ? p.aj_V  : p.am_V;
    float* E = isJob ? p.Ej : p.Em;
    const int n  = isJob ? NJ : NM;
    const int b0 = isJob ? (int)blockIdx.x : (int)blockIdx.x - GB_J;

    const int r0 = b0 * ROWS_PER_BLK + 4 * (int)threadIdx.x;
    const bool v = r0 < n;
    const size_t a0 = v ? (size_t)r0 : 0;
    const size_t d  = v ? 1 : 0;

    // issue all 16 global loads first (latency overlaps the qk prologue)
    v2f x0[16], x1[16];
    load16_v2(X, a0, a0 + d, x0);
    load16_v2(X, a0 + 2 * d, a0 + 3 * d, x1);

    __shared__ float qks[16];
    if (threadIdx.x < 16) {
        const float* Wq = isJob ? p.aj_Wq : p.am_Wq;
        const float* bq = isJob ? p.aj_bq : p.am_bq;
        const int i = threadIdx.x;
        float a = bq[i];
#pragma unroll
        for (int k = 0; k < 16; ++k) a = fmaf(Wq[i * 16 + k], p.last_j[k], a);
        qks[i] = a;
    }
    __syncthreads();
    float qk[16];
#pragma unroll
    for (int i = 0; i < 16; ++i) qk[i] = qks[i];

    v2f e0[16], e1[16];
    emb16_v2(x0, W1, b1, W2, b2, e0);
    emb16_v2(x1, W1, b1, W2, b2, e1);
    if (CACHE) ecache_store4(E + (size_t)b0 * EBLK, (int)threadIdx.x, e0, e1);
    v2f lg0 = att_logit_v2(e0, qk, Wr, V);
    v2f lg1 = att_logit_v2(e1, qk, Wr, V);
    // |logit| <= sum|V| ~ 0.6 -> exp never overflows; no max-shift needed.
    v2f w01, w23;
    w01.x = v ? __expf(lg0.x) : 0.0f;
    w01.y = v ? __expf(lg0.y) : 0.0f;
    w23.x = v ? __expf(lg1.x) : 0.0f;
    w23.y = v ? __expf(lg1.y) : 0.0f;
    float l = (w01.x + w01.y) + (w23.x + w23.y);
    float s[16];
    wsum4(e0, e1, w01, w23, s);

    block_sum17(l, s, p.S + (isJob ? P1J : P1M) + (size_t)b0 * 17);
}

// ---------------------------------------------------------------------------
// Combine partials -> g (g1 or g2) -> next-stage qk vector. Single block.
// ---------------------------------------------------------------------------
__global__ __launch_bounds__(BLK) void k_combine_g(Params p, int phase) {
    const float* PJ = p.S + P1J;
    const float* PM = p.S + P1M;
    float lJ = 0.0f, lM = 0.0f, sJ[16], sM[16];
#pragma unroll
    for (int c = 0; c < 16; ++c) { sJ[c] = 0.0f; sM[c] = 0.0f; }
    for (int i = threadIdx.x; i < GB_J; i += BLK) {
        lJ += PJ[i * 17];
#pragma unroll
        for (int c = 0; c < 16; ++c) sJ[c] += PJ[i * 17 + 1 + c];
    }
    for (int i = threadIdx.x; i < GB_M; i += BLK) {
        lM += PM[i * 17];
#pragma unroll
        for (int c = 0; c < 16; ++c) sM[c] += PM[i * 17 + 1 + c];
    }
    __shared__ float totJ[17], totM[17];
    block_sum17(lJ, sJ, totJ);
    block_sum17(lM, sM, totM);
    __syncthreads();

    __shared__ float cb[48], gbuf[16];
    if (threadIdx.x < 16) {
        int i = threadIdx.x;
        cb[i]      = phase ? p.S[S_EJS + i] : p.last_j[i];
        cb[16 + i] = totJ[1 + i] / totJ[0];   // softmax-weighted sum / partition
        cb[32 + i] = totM[1 + i] / totM[0];
    }
    __syncthreads();
    const float* gW  = phase ? p.g2W : p.g1W;
    const float* gbv = phase ? p.g2b : p.g1b;
    if (threadIdx.x < 16) {
        int i = threadIdx.x;
        float a = gbv[i];
#pragma unroll
        for (int k = 0; k < 48; ++k) a = fmaf(gW[i * 48 + k], cb[k], a);
        gbuf[i] = fast_tanh(a);
    }
    __syncthreads();
    const float* Wq = phase ? p.ma_Wq : p.ja_Wq;
    const float* bq = phase ? p.ma_bq : p.ja_bq;
    const int off = phase ? S_QKMA : S_QKJA;
    if (threadIdx.x < 16) {
        int i = threadIdx.x;
        float a = bq[i];
#pragma unroll
        for (int k = 0; k < 16; ++k) a = fmaf(Wq[i * 16 + k], gbuf[k], a);
        p.S[off + i] = a;
    }
}

// ---------------------------------------------------------------------------
// K3: job pointer logits -> masked argmax + sum-exp partials. Rows (4t..4t+3).
// Mask load issued BEFORE the E loads (in flight together).
// ---------------------------------------------------------------------------
template <bool CACHE>
__global__ __launch_bounds__(BLK) void k_jlogits(Params p) {
    const int r0 = blockIdx.x * ROWS_PER_BLK + 4 * (int)threadIdx.x;
    const bool v = r0 < NJ;
    const size_t a0 = v ? (size_t)r0 : 0;
    const size_t d  = v ? 1 : 0;

    int4 mq = make_int4(0, 0, 0, 0);
    if (v) mq = *reinterpret_cast<const int4*>(p.mask + r0);   // r0 mult of 4 -> 16B aligned

    v2f e0[16], e1[16];
    if (CACHE) {
        ecache_load4(p.Ej + (size_t)blockIdx.x * EBLK, (int)threadIdx.x, e0, e1);
    } else {
        v2f x0[16], x1[16];
        load16_v2(p.jobs, a0, a0 + d, x0);
        load16_v2(p.jobs, a0 + 2 * d, a0 + 3 * d, x1);
        emb16_v2(x0, p.jW1, p.jb1, p.jW2, p.jb2, e0);
        emb16_v2(x1, p.jW1, p.jb1, p.jW2, p.jb2, e1);
    }
    float qk[16];
#pragma unroll
    for (int i = 0; i < 16; ++i) qk[i] = p.S[S_QKJA + i];

    v2f lg0 = att_logit_v2(e0, qk, p.ja_Wr, p.ja_V);
    v2f lg1 = att_logit_v2(e1, qk, p.ja_Wr, p.ja_V);

    const bool m0 = v && (mq.x != 0);
    const bool m1 = v && (mq.y != 0);
    const bool m2 = v && (mq.z != 0);
    const bool m3 = v && (mq.w != 0);
    float l = (m0 ? __expf(lg0.x) : 0.0f) + (m1 ? __expf(lg0.y) : 0.0f)
            + (m2 ? __expf(lg1.x) : 0.0f) + (m3 ? __expf(lg1.y) : 0.0f);
    float am0 = m0 ? lg0.x : NEGV - 1.0f;  // invalid rows below masked NEG
    float am1 = m1 ? lg0.y : NEGV - 1.0f;
    float am2 = m2 ? lg1.x : NEGV - 1.0f;
    float am3 = m3 ? lg1.y : NEGV - 1.0f;
    float best = am0; int bi = r0;
    if (am1 > best) { best = am1; bi = r0 + 1; }
    if (am2 > best) { best = am2; bi = r0 + 2; }
    if (am3 > best) { best = am3; bi = r0 + 3; }

    l = wave_reduce_sum(l);
    wave_reduce_argmax(best, bi);
    __shared__ float rl[4], rv[4];
    __shared__ int ri[4];
    int w = threadIdx.x >> 6, ln = threadIdx.x & 63;
    if (ln == 0) { rl[w] = l; rv[w] = best; ri[w] = bi; }
    __syncthreads();
    if (threadIdx.x == 0) {
        float L = rl[0] + rl[1] + rl[2] + rl[3];
        float vv = rv[0]; int i = ri[0];
#pragma unroll
        for (int k = 1; k < 4; ++k)
            if (rv[k] > vv || (rv[k] == vv && ri[k] < i)) { vv = rv[k]; i = ri[k]; }
        p.S[P2V + blockIdx.x] = vv;
        p.S[P2I + blockIdx.x] = (float)i;   // exact: i < 2^24
        p.S[P2L + blockIdx.x] = L;
    }
}

// ---------------------------------------------------------------------------
// C2: global argmax over job logits; logp_j; e_js = emb(jobs[sel_j]); qk2j/qk2m
// ---------------------------------------------------------------------------
__global__ __launch_bounds__(BLK) void k_combine2(Params p) {
    float v = -3.4e38f; int vi = 0x7fffffff; float l = 0.0f;
    for (int i = threadIdx.x; i < GB_J; i += BLK) {
        float pv = p.S[P2V + i];
        int pi = (int)p.S[P2I + i];
        if (pv > v || (pv == v && pi < vi)) { v = pv; vi = pi; }
        l += p.S[P2L + i];
    }
    l = block_sum(l);
    block_argmax(v, vi);
    const int sel = vi;

    __shared__ float xb[16], hb[16], eb[16];
    if (threadIdx.x < 16) xb[threadIdx.x] = p.jobs[(size_t)sel * 16 + threadIdx.x];
    __syncthreads();
    if (threadIdx.x < 16) {
        int i = threadIdx.x;
        float a = p.jb1[i];
#pragma unroll
        for (int k = 0; k < 16; ++k) a = fmaf(p.jW1[i * 16 + k], xb[k], a);
        hb[i] = fast_tanh(a);
    }
    __syncthreads();
    if (threadIdx.x < 16) {
        int i = threadIdx.x;
        float a = p.jb2[i];
#pragma unroll
        for (int k = 0; k < 16; ++k) a = fmaf(p.jW2[i * 16 + k], hb[k], a);
        float e = fast_tanh(a);
        eb[i] = e;
        p.S[S_EJS + i] = e;
    }
    __syncthreads();
    if (threadIdx.x < 16) {
        int i = threadIdx.x;
        float a1 = p.aj_bq[i], a2 = p.am_bq[i];
#pragma unroll
        for (int k = 0; k < 16; ++k) {
            a1 = fmaf(p.aj_Wq[i * 16 + k], eb[k], a1);
            a2 = fmaf(p.am_Wq[i * 16 + k], eb[k], a2);
        }
        p.S[S_QK2J + i] = a1;
        p.S[S_QK2M + i] = a2;
    }
    if (threadIdx.x == 0) {
        p.S[S_LOGPJ] = v - logf(l);     // log_softmax at the argmax
        p.S[S_SELJ] = (float)sel;
    }
}

// ---------------------------------------------------------------------------
// K4: glimpse-2 over jobs (aj_*) and machines (am_*), query e_js. Rows (4t..4t+3).
// Writes partials into the (already consumed) P1 buffers.
// ---------------------------------------------------------------------------
template <bool CACHE>
__global__ __launch_bounds__(BLK) void k_glimpse2(Params p) {
    const bool isJob = blockIdx.x < GB_J;
    const float* Wr = isJob ? p.aj_Wr : p.am_Wr;
    const float* V  = isJob ? p.aj_V  : p.am_V;
    const float* E  = isJob ? p.Ej : p.Em;
    const float* X  = isJob ? p.jobs : p.machines;
    const float* W1 = isJob ? p.jW1 : p.mW1;
    const float* b1 = isJob ? p.jb1 : p.mb1;
    const float* W2 = isJob ? p.jW2 : p.mW2;
    const float* b2 = isJob ? p.jb2 : p.mb2;
    const int n  = isJob ? NJ : NM;
    const int b0 = isJob ? (int)blockIdx.x : (int)blockIdx.x - GB_J;
    const int qoff = isJob ? S_QK2J : S_QK2M;

    const int r0 = b0 * ROWS_PER_BLK + 4 * (int)threadIdx.x;
    const bool v = r0 < n;
    const size_t a0 = v ? (size_t)r0 : 0;
    const size_t d  = v ? 1 : 0;

    v2f e0[16], e1[16];
    if (CACHE) {
        ecache_load4(E + (size_t)b0 * EBLK, (int)threadIdx.x, e0, e1);
    } else {
        v2f x0[16], x1[16];
        load16_v2(X, a0, a0 + d, x0);
        load16_v2(X, a0 + 2 * d, a0 + 3 * d, x1);
        emb16_v2(x0, W1, b1, W2, b2, e0);
        emb16_v2(x1, W1, b1, W2, b2, e1);
    }
    float qk[16];
#pragma unroll
    for (int i = 0; i < 16; ++i) qk[i] = p.S[qoff + i];

    v2f lg0 = att_logit_v2(e0, qk, Wr, V);
    v2f lg1 = att_logit_v2(e1, qk, Wr, V);
    v2f w01, w23;
    w01.x = v ? __expf(lg0.x) : 0.0f;
    w01.y = v ? __expf(lg0.y) : 0.0f;
    w23.x = v ? __expf(lg1.x) : 0.0f;
    w23.y = v ? __expf(lg1.y) : 0.0f;
    float l = (w01.x + w01.y) + (w23.x + w23.y);
    float s[16];
    wsum4(e0, e1, w01, w23, s);

    block_sum17(l, s, p.S + (isJob ? P1J : P1M) + (size_t)b0 * 17);
}

// ---------------------------------------------------------------------------
// K5: machine logits -> argmax + sum-exp partials. Rows (4t..4t+3).
// Writes into the (already consumed) P2 buffers.
// ---------------------------------------------------------------------------
template <bool CACHE>
__global__ __launch_bounds__(BLK) void k_mlogits(Params p) {
    const int r0 = blockIdx.x * ROWS_PER_BLK + 4 * (int)threadIdx.x;
    const bool v = r0 < NM;
    const size_t a0 = v ? (size_t)r0 : 0;
    const size_t d  = v ? 1 : 0;

    v2f e0[16], e1[16];
    if (CACHE) {
        ecache_load4(p.Em + (size_t)blockIdx.x * EBLK, (int)threadIdx.x, e0, e1);
    } else {
        v2f x0[16], x1[16];
        load16_v2(p.machines, a0, a0 + d, x0);
        load16_v2(p.machines, a0 + 2 * d, a0 + 3 * d, x1);
        emb16_v2(x0, p.mW1, p.mb1, p.mW2, p.mb2, e0);
        emb16_v2(x1, p.mW1, p.mb1, p.mW2, p.mb2, e1);
    }
    float qk[16];
#pragma unroll
    for (int i = 0; i < 16; ++i) qk[i] = p.S[S_QKMA + i];

    v2f lg0 = att_logit_v2(e0, qk, p.ma_Wr, p.ma_V);
    v2f lg1 = att_logit_v2(e1, qk, p.ma_Wr, p.ma_V);
    float l = (v ? __expf(lg0.x) : 0.0f) + (v ? __expf(lg0.y) : 0.0f)
            + (v ? __expf(lg1.x) : 0.0f) + (v ? __expf(lg1.y) : 0.0f);
    float am0 = v ? lg0.x : -3.4e38f;
    float am1 = v ? lg0.y : -3.4e38f;
    float am2 = v ? lg1.x : -3.4e38f;
    float am3 = v ? lg1.y : -3.4e38f;
    float best = am0; int bi = r0;
    if (am1 > best) { best = am1; bi = r0 + 1; }
    if (am2 > best) { best = am2; bi = r0 + 2; }
    if (am3 > best) { best = am3; bi = r0 + 3; }

    l = wave_reduce_sum(l);
    wave_reduce_argmax(best, bi);
    __shared__ float rl[4], rv[4];
    __shared__ int ri[4];
    int w = threadIdx.x >> 6, ln = threadIdx.x & 63;
    if (ln == 0) { rl[w] = l; rv[w] = best; ri[w] = bi; }
    __syncthreads();
    if (threadIdx.x == 0) {
        float L = rl[0] + rl[1] + rl[2] + rl[3];
        float vv = rv[0]; int i = ri[0];
#pragma unroll
        for (int k = 1; k < 4; ++k)
            if (rv[k] > vv || (rv[k] == vv && ri[k] < i)) { vv = rv[k]; i = ri[k]; }
        p.S[P2V + blockIdx.x] = vv;
        p.S[P2I + blockIdx.x] = (float)i;
        p.S[P2L + blockIdx.x] = L;
    }
}

// ---------------------------------------------------------------------------
// C4: final combine -> outputs [sel_j, sel_m, logpas] as float32
// ---------------------------------------------------------------------------
__global__ __launch_bounds__(BLK) void k_combine4(Params p) {
    float v = -3.4e38f; int vi = 0x7fffffff; float l = 0.0f;
    for (int i = threadIdx.x; i < GB_M; i += BLK) {
        float pv = p.S[P2V + i];
        int pi = (int)p.S[P2I + i];
        if (pv > v || (pv == v && pi < vi)) { v = pv; vi = pi; }
        l += p.S[P2L + i];
    }
    l = block_sum(l);
    block_argmax(v, vi);
    if (threadIdx.x == 0) {
        p.out[0] = p.S[S_SELJ];
        p.out[1] = (float)vi;
        p.out[2] = p.S[S_LOGPJ] + (v - logf(l));
    }
}

// ---------------------------------------------------------------------------
extern "C" void kernel_launch(void* const* d_in, const int* in_sizes, int n_in,
                              void* d_out, int out_size, void* d_ws, size_t ws_size,
                              hipStream_t stream) {
    Params p;
    p.jobs     = (const float*)d_in[0];
    p.machines = (const float*)d_in[1];
    p.mask     = (const int*)d_in[2];
    p.jW1 = (const float*)d_in[3];  p.jb1 = (const float*)d_in[4];
    p.jW2 = (const float*)d_in[5];  p.jb2 = (const float*)d_in[6];
    p.mW1 = (const float*)d_in[7];  p.mb1 = (const float*)d_in[8];
    p.mW2 = (const float*)d_in[9];  p.mb2 = (const float*)d_in[10];
    p.aj_Wq = (const float*)d_in[11]; p.aj_bq = (const float*)d_in[12];
    p.aj_Wr = (const float*)d_in[13]; p.aj_V  = (const float*)d_in[14];
    p.am_Wq = (const float*)d_in[15]; p.am_bq = (const float*)d_in[16];
    p.am_Wr = (const float*)d_in[17]; p.am_V  = (const float*)d_in[18];
    p.ja_Wq = (const float*)d_in[19]; p.ja_bq = (const float*)d_in[20];
    p.ja_Wr = (const float*)d_in[21]; p.ja_V  = (const float*)d_in[22];
    p.ma_Wq = (const float*)d_in[23]; p.ma_bq = (const float*)d_in[24];
    p.ma_Wr = (const float*)d_in[25]; p.ma_V  = (const float*)d_in[26];
    p.g1W = (const float*)d_in[27]; p.g1b = (const float*)d_in[28];
    p.g2W = (const float*)d_in[29]; p.g2b = (const float*)d_in[30];
    p.last_j = (const float*)d_in[31];
    p.S = (float*)d_ws;
    p.Ej = (float*)d_ws + E_OFF;
    p.Em = p.Ej + (size_t)GB_J * EBLK;
    p.out = (float*)d_out;

    const size_t needed = (E_OFF + (size_t)GB_TOT * EBLK) * sizeof(float);
    const bool cache = ws_size >= needed;

    if (cache) {
        k_emb_g1<true><<<GB_TOT, BLK, 0, stream>>>(p);
        k_combine_g<<<1, BLK, 0, stream>>>(p, 0);
        k_jlogits<true><<<GB_J, BLK, 0, stream>>>(p);
        k_combine2<<<1, BLK, 0, stream>>>(p);
        k_glimpse2<true><<<GB_TOT, BLK, 0, stream>>>(p);
        k_combine_g<<<1, BLK, 0, stream>>>(p, 1);
        k_mlogits<true><<<GB_M, BLK, 0, stream>>>(p);
        k_combine4<<<1, BLK, 0, stream>>>(p);
    } else {
        k_emb_g1<false><<<GB_TOT, BLK, 0, stream>>>(p);
        k_combine_g<<<1, BLK, 0, stream>>>(p, 0);
        k_jlogits<false><<<GB_J, BLK, 0, stream>>>(p);
        k_combine2<<<1, BLK, 0, stream>>>(p);
        k_glimpse2<false><<<GB_TOT, BLK, 0, stream>>>(p);
        k_combine_g<<<1, BLK, 0, stream>>>(p, 1);
        k_mlogits<false><<<GB_M, BLK, 0, stream>>>(p);
        k_combine4<<<1, BLK, 0, stream>>>(p);
    }
}